// Round 6
// baseline (396.794 us; speedup 1.0000x reference)
//
#include <hip/hip_runtime.h>
#include <hip/hip_bf16.h>
#include <math.h>

#define DIM    256
#define DEPTH  5
#define FANOUT 10
#define VOCAB  257
#define BB     16
#define TT     2048
#define NEXP   8
#define HID    512
#define TOPK   2
#define CAP    5   // ceil(16*2/8*1.1)

__device__ __forceinline__ float sigm(float x) { return 1.f / (1.f + expf(-x)); }

// 256x256 matvec partial: 1024 threads = 16 ksegs x 64 col-quads.
// Depth-8 float4 batches inside a KEPT loop (#pragma unroll 1): 2 latency
// exposures per matvec. R1-R3 lesson: fully-unrolled forms get ALL loads
// hoisted and spill 10MB/dispatch; only a real loop boundary stops the hoist.
__device__ __forceinline__ void mv8x2(const float* sv, const float* __restrict__ W,
                                      int kseg, int cq, float red[16][DIM]) {
  const float* Wp = W + (size_t)kseg * 16 * DIM + cq * 4;
  float4 acc = {0.f, 0.f, 0.f, 0.f};
#pragma unroll 1
  for (int h = 0; h < 2; ++h) {
    float4 wv[8];
#pragma unroll
    for (int i = 0; i < 8; ++i)
      wv[i] = *(const float4*)(Wp + (size_t)(h * 8 + i) * DIM);
#pragma unroll
    for (int i = 0; i < 8; ++i) {
      float s = sv[kseg * 16 + h * 8 + i];
      acc.x = fmaf(s, wv[i].x, acc.x);
      acc.y = fmaf(s, wv[i].y, acc.y);
      acc.z = fmaf(s, wv[i].z, acc.z);
      acc.w = fmaf(s, wv[i].w, acc.w);
    }
    __builtin_amdgcn_sched_barrier(0);
  }
  *(float4*)&red[kseg][cq * 4] = acc;
}

__device__ __forceinline__ float sum16(const float red[16][DIM], int d) {
  float s = 0.f;
#pragma unroll
  for (int g = 0; g < 16; ++g) s += red[g][d];
  return s;
}

// ------ collapsed fractal + context + root2 init + token-CSR build -----------
__global__ void __launch_bounds__(1024) k_fractal(
    const int* __restrict__ tokens, const float* __restrict__ embed,
    const float* __restrict__ pin_w, const float* __restrict__ pin_b,
    const float* __restrict__ pch_w, const float* __restrict__ pch_b,
    const float* __restrict__ depth_bias,
    const float* __restrict__ v_w, const float* __restrict__ v_b,
    const float* __restrict__ o_w, const float* __restrict__ o_b,
    const float* __restrict__ level_gate, const float* __restrict__ depth_gate,
    const float* __restrict__ in_proj_w, const float* __restrict__ in_proj_b,
    const float* __restrict__ out_proj_w, const float* __restrict__ out_proj_b,
    const float* __restrict__ ln_g, const float* __restrict__ ln_b,
    const float* __restrict__ ic_gate,
    float* __restrict__ rootA, float* __restrict__ root2,
    int* __restrict__ bidx, int* __restrict__ boff) {
  int b = blockIdx.x;
  int tid = threadIdx.x;
  int d = tid & 255;
  int ks = tid >> 8;       // 0..3 (consumer / in_proj layout)
  int k0 = ks * 64;
  int kseg = tid >> 6;     // 0..15 (mv8x2 layout)
  int cq = tid & 63;
  __shared__ int cnt[VOCAB];
  __shared__ float sv[DIM];
  __shared__ float basev[DIM];
  __shared__ float ym[DEPTH][DIM];
  __shared__ float q0v[DIM], kh[DEPTH][DIM], vh[DEPTH][DIM];
  __shared__ float red11[4][11][DIM];   // in_proj reduction; also aliases red16
  __shared__ float zsv[DIM];
  __shared__ float aw[16];
  __shared__ float redl[8];
  __shared__ int offb[VOCAB + 1];
  __shared__ int woff[VOCAB];
  float (*red16)[DIM] = reinterpret_cast<float(*)[DIM]>(&red11[0][0][0]); // 16KB of 44KB

  // ---- context = (histogram @ embed) / T, branch-free ----
  for (int i = tid; i < VOCAB; i += 1024) cnt[i] = 0;
  __syncthreads();
  for (int t = tid; t < TT; t += 1024) atomicAdd(&cnt[tokens[b * TT + t]], 1);
  __syncthreads();
  {
    const float* Ep = embed + (size_t)kseg * 16 * DIM + cq * 4;
    float4 acc = {0.f, 0.f, 0.f, 0.f};
#pragma unroll 1
    for (int h = 0; h < 2; ++h) {
      float4 ev[8];
#pragma unroll
      for (int i = 0; i < 8; ++i)
        ev[i] = *(const float4*)(Ep + (size_t)(h * 8 + i) * DIM);
#pragma unroll
      for (int i = 0; i < 8; ++i) {
        float cv = (float)cnt[kseg * 16 + h * 8 + i];
        acc.x = fmaf(cv, ev[i].x, acc.x);
        acc.y = fmaf(cv, ev[i].y, acc.y);
        acc.z = fmaf(cv, ev[i].z, acc.z);
        acc.w = fmaf(cv, ev[i].w, acc.w);
      }
      __builtin_amdgcn_sched_barrier(0);
    }
    *(float4*)&red16[kseg][cq * 4] = acc;
  }
  __syncthreads();
  if (ks == 0) {
    float s = sum16(red16, d);
    s = fmaf((float)cnt[256], embed[(size_t)256 * DIM + d], s);
    sv[d] = s * (1.0f / (float)TT);
  }
  __syncthreads();

  mv8x2(sv, pin_w, kseg, cq, red16);
  __syncthreads();
  if (ks == 0) {
    float base = sum16(red16, d) + pin_b[d];
    basev[d] = base;
    float u = (base + depth_bias[4 * DIM + d] + pch_b[d]) * sigm(level_gate[4]);
    sv[d] = fmaxf(u, 0.f);
  }
  __syncthreads();
  mv8x2(sv, o_w, kseg, cq, red16);
  __syncthreads();
  if (ks == 0) {
    float y = sum16(red16, d) + o_b[d];
    ym[4][d] = y;
    sv[d] = y;
  }
  __syncthreads();
  for (int l = 3; l >= 0; --l) {
    mv8x2(sv, v_w, kseg, cq, red16);
    __syncthreads();
    if (ks == 0) {
      float vv = sum16(red16, d) + v_b[d];
      sv[d] = sigm(depth_gate[l * DIM + d]) * vv;   // uniform softmax -> child = v
    }
    __syncthreads();
    mv8x2(sv, pch_w, kseg, cq, red16);
    __syncthreads();
    if (ks == 0) {
      float t = sum16(red16, d) + pch_b[d];
      float u = (basev[d] + depth_bias[l * DIM + d] + t) * sigm(level_gate[l]);
      sv[d] = fmaxf(u, 0.f);
    }
    __syncthreads();
    mv8x2(sv, o_w, kseg, cq, red16);
    __syncthreads();
    if (ks == 0) {
      float y = sum16(red16, d) + o_b[d];
      ym[l][d] = y;
      sv[d] = y;
    }
    __syncthreads();
  }
  // ---- in_proj, ALL levels in ONE pass over the weights (8-deep batches) ----
  {
    float aq = 0.f;
    float ak0 = 0.f, ak1 = 0.f, ak2 = 0.f, ak3 = 0.f, ak4 = 0.f;
    float av0 = 0.f, av1 = 0.f, av2 = 0.f, av3 = 0.f, av4 = 0.f;
#pragma unroll
    for (int h = 0; h < 8; ++h) {
      int kb = k0 + h * 8;
      float wq[8], wk[8], wv8[8];
#pragma unroll
      for (int i = 0; i < 8; ++i) {
        const float* wrow = in_proj_w + (size_t)(kb + i) * 768;
        wq[i] = wrow[d]; wk[i] = wrow[256 + d]; wv8[i] = wrow[512 + d];
      }
#pragma unroll
      for (int i = 0; i < 8; ++i) {
        float z0 = ym[0][kb + i];
        aq  = fmaf(z0, wq[i], aq);
        ak0 = fmaf(z0, wk[i], ak0);
        av0 = fmaf(z0, wv8[i], av0);
        float z1 = ym[1][kb + i];
        ak1 = fmaf(z1, wk[i], ak1);
        av1 = fmaf(z1, wv8[i], av1);
        float z2 = ym[2][kb + i];
        ak2 = fmaf(z2, wk[i], ak2);
        av2 = fmaf(z2, wv8[i], av2);
        float z3 = ym[3][kb + i];
        ak3 = fmaf(z3, wk[i], ak3);
        av3 = fmaf(z3, wv8[i], av3);
        float z4 = ym[4][kb + i];
        ak4 = fmaf(z4, wk[i], ak4);
        av4 = fmaf(z4, wv8[i], av4);
      }
    }
    red11[ks][0][d] = ak0; red11[ks][1][d] = ak1; red11[ks][2][d] = ak2;
    red11[ks][3][d] = ak3; red11[ks][4][d] = ak4;
    red11[ks][5][d] = av0; red11[ks][6][d] = av1; red11[ks][7][d] = av2;
    red11[ks][8][d] = av3; red11[ks][9][d] = av4;
    red11[ks][10][d] = aq;
  }
  __syncthreads();
  for (int idx = tid; idx < 11 * DIM; idx += 1024) {
    int c = idx >> 8, dd = idx & 255;
    float sum = red11[0][c][dd] + red11[1][c][dd] + red11[2][c][dd] + red11[3][c][dd];
    if (c < 5)       kh[c][dd]     = sum + in_proj_b[256 + dd];
    else if (c < 10) vh[c - 5][dd] = sum + in_proj_b[512 + dd];
    else             q0v[dd]       = sum + in_proj_b[dd];
  }
  __syncthreads();
  {
    int wid = tid >> 6;
    if (wid < 10) {
      int h = wid / 5, l = wid - h * 5;
      int lane = tid & 63;
      float s = q0v[h * 128 + lane] * kh[l][h * 128 + lane];
      s = fmaf(q0v[h * 128 + 64 + lane], kh[l][h * 128 + 64 + lane], s);
      for (int o = 32; o > 0; o >>= 1) s += __shfl_down(s, o, 64);
      if (lane == 0) aw[wid] = s * 0.08838834764831845f;  // 1/sqrt(128)
    }
  }
  __syncthreads();
  if (tid < 2) {
    float m = aw[tid * 5];
    for (int l = 1; l < 5; ++l) m = fmaxf(m, aw[tid * 5 + l]);
    float e[5], ssum = 0.f;
    for (int l = 0; l < 5; ++l) { e[l] = expf(aw[tid * 5 + l] - m); ssum += e[l]; }
    for (int l = 0; l < 5; ++l) aw[tid * 5 + l] = e[l] / ssum;
  }
  __syncthreads();
  if (ks == 0) {
    int h = d >> 7;
    float z2 = 0.f;
    for (int l = 0; l < 5; ++l) z2 = fmaf(aw[h * 5 + l], vh[l][d], z2);
    sv[d] = z2;
  }
  __syncthreads();
  mv8x2(sv, out_proj_w, kseg, cq, red16);
  __syncthreads();
  if (ks == 0) {
    float z2p = sum16(red16, d) + out_proj_b[d];
    zsv[d] = ym[0][d] + z2p;
  }
  __syncthreads();
  float zs = 0.f, df = 0.f, mu = 0.f;
  if (tid < 256) {
    zs = zsv[tid];
    float v = zs;
    for (int o = 32; o > 0; o >>= 1) v += __shfl_down(v, o, 64);
    if ((tid & 63) == 0) redl[tid >> 6] = v;
  }
  __syncthreads();
  if (tid < 256) {
    mu = (redl[0] + redl[1] + redl[2] + redl[3]) * (1.f / 256.f);
    df = zs - mu;
  }
  __syncthreads();
  if (tid < 256) {
    float v = df * df;
    for (int o = 32; o > 0; o >>= 1) v += __shfl_down(v, o, 64);
    if ((tid & 63) == 0) redl[tid >> 6] = v;
  }
  __syncthreads();
  if (tid < 256) {
    float var = (redl[0] + redl[1] + redl[2] + redl[3]) * (1.f / 256.f);
    float zn = df / sqrtf(var + 1e-5f) * ln_g[tid] + ln_b[tid];
    float r = ym[0][tid] + sigm(ic_gate[0]) * zn;
    rootA[b * DIM + tid] = r;
    root2[b * DIM + tid] = r;   // experts atomically add on top
  }
  // ---- token CSR for fused logits-scatter ----
  __syncthreads();
  if (tid == 0) {
    int a = 0;
    for (int v = 0; v < VOCAB; ++v) { offb[v] = a; a += cnt[v]; }
    offb[VOCAB] = a;              // == TT
  }
  __syncthreads();
  if (tid <= VOCAB) boff[b * (VOCAB + 1) + tid] = offb[tid];
  if (tid < VOCAB) woff[tid] = offb[tid];
  __syncthreads();
  for (int t = tid; t < TT; t += 1024) {
    int tok = tokens[b * TT + t];
    int p = atomicAdd(&woff[tok], 1);
    bidx[b * TT + p] = t;         // bucket order arbitrary; output order-invariant
  }
}

// ---- MoE GEMM1 + fused gating: 64 blocks = 8 experts x 8 tiles of 64 cols ----
// Gating inputs (rootA 16KB + gate_w 8KB) staged to LDS in one coalesced pass
// (old form: 128 threads x 256 serial global loads = latency chain). Summation
// order identical to the original k_gate -> bit-exact top-k ties.
__global__ void __launch_bounds__(256) k_expert1(
    const float* __restrict__ rootA,
    const float* __restrict__ gate_w, const float* __restrict__ gate_b,
    const float* __restrict__ ew1, const float* __restrict__ eb1,
    int* __restrict__ etok, float* __restrict__ ewt,
    float* __restrict__ hid_ws) {
  int bx = blockIdx.x;
  int e = bx >> 3, jt = bx & 7, j0 = jt * 64;
  int tid = threadIdx.x, w = tid >> 6, lane = tid & 63;
  __shared__ float rlds[BB * DIM];      // 16KB rootA copy
  __shared__ float gwlds[DIM * NEXP];   // 8KB gate_w copy
  __shared__ float xin[CAP][DIM];
  __shared__ float red[CAP][4][64];
  __shared__ float sc[BB * NEXP];
  __shared__ float gs[BB * TOPK];
  __shared__ int gidx[BB * TOPK];
  __shared__ int stok[CAP];
  __shared__ float swt[CAP];
  for (int idx = tid; idx < BB * DIM / 4; idx += 256)
    *(float4*)&rlds[idx * 4] = *(const float4*)&rootA[idx * 4];
  for (int idx = tid; idx < DIM * NEXP / 4; idx += 256)
    *(float4*)&gwlds[idx * 4] = *(const float4*)&gate_w[idx * 4];
  __syncthreads();
  if (tid < BB * NEXP) {
    int b = tid >> 3, ep = tid & 7;
    float chunk[8];
#pragma unroll
    for (int g = 0; g < 8; ++g) {
      float acc = 0.f;
#pragma unroll 8
      for (int i = 0; i < 32; ++i) {
        int k = g * 32 + i;
        acc = fmaf(rlds[b * DIM + k], gwlds[k * NEXP + ep], acc);
      }
      chunk[g] = acc;
    }
    float s = gate_b[ep];
#pragma unroll
    for (int g = 0; g < 8; ++g) s += chunk[g];
    sc[tid] = s;
  }
  __syncthreads();
  if (tid < BB) {  // top-2 + softmax per batch (identical order to old k_gate)
    int bb = tid;
    int i0 = 0; float v0 = sc[bb * 8 + 0];
    for (int ee = 1; ee < 8; ++ee) { float v = sc[bb * 8 + ee]; if (v > v0) { v0 = v; i0 = ee; } }
    int i1 = -1; float v1 = -1e30f;
    for (int ee = 0; ee < 8; ++ee) {
      if (ee == i0) continue;
      float v = sc[bb * 8 + ee];
      if (v > v1) { v1 = v; i1 = ee; }
    }
    float e1v = expf(v1 - v0);
    float s = 1.f + e1v;
    gs[bb * 2 + 0] = 1.f / s;  gidx[bb * 2 + 0] = i0;
    gs[bb * 2 + 1] = e1v / s;  gidx[bb * 2 + 1] = i1;
  }
  __syncthreads();
  if (tid == 0) {  // top-CAP for own expert: bitmask, value desc / index asc
    unsigned used = 0u;
    for (int s = 0; s < CAP; ++s) {
      int bi = 0; float bv = -1e30f;
      for (int i = 0; i < 32; ++i) {
        if (used & (1u << i)) continue;
        float v = (gidx[i] == e) ? gs[i] : -1.0f;
        if (v > bv) { bv = v; bi = i; }
      }
      used |= (1u << bi);
      stok[s] = bi >> 1;
      swt[s] = bv > 0.f ? bv : 0.f;
    }
  }
  __syncthreads();
  if (jt == 0 && tid < CAP) {  // publish for k_expert2
    etok[e * CAP + tid] = stok[tid];
    ewt[e * CAP + tid] = swt[tid];
  }
  for (int idx = tid; idx < CAP * DIM; idx += 256) {
    int s = idx >> 8, k = idx & 255;
    xin[s][k] = rlds[stok[s] * DIM + k];
  }
  __syncthreads();
  float a0 = 0.f, a1 = 0.f, a2 = 0.f, a3 = 0.f, a4 = 0.f;
  const float* W = ew1 + (size_t)e * DIM * HID + j0 + lane;  // row k -> +k*HID
  int kbase = w * 64;
#pragma unroll
  for (int h = 0; h < 8; ++h) {
    float wv[8];
#pragma unroll
    for (int i = 0; i < 8; ++i) wv[i] = W[(size_t)(kbase + h * 8 + i) * HID];
#pragma unroll
    for (int i = 0; i < 8; ++i) {
      int k = kbase + h * 8 + i;
      a0 = fmaf(xin[0][k], wv[i], a0);
      a1 = fmaf(xin[1][k], wv[i], a1);
      a2 = fmaf(xin[2][k], wv[i], a2);
      a3 = fmaf(xin[3][k], wv[i], a3);
      a4 = fmaf(xin[4][k], wv[i], a4);
    }
  }
  red[0][w][lane] = a0; red[1][w][lane] = a1; red[2][w][lane] = a2;
  red[3][w][lane] = a3; red[4][w][lane] = a4;
  __syncthreads();
  for (int idx = tid; idx < CAP * 64; idx += 256) {
    int s = idx >> 6, j = idx & 63;
    float sum = red[s][0][j] + red[s][1][j] + red[s][2][j] + red[s][3][j]
              + eb1[e * HID + j0 + j];
    hid_ws[((size_t)(e * CAP + s)) * HID + j0 + j] = fmaxf(sum, 0.f);
  }
}

// ----- MoE GEMM2 + combine: 64 blocks; atomic add into root2[tok] -------------
__global__ void __launch_bounds__(256) k_expert2(
    const float* __restrict__ hid_ws,
    const float* __restrict__ ew2, const float* __restrict__ eb2,
    const float* __restrict__ ewt, const int* __restrict__ etok,
    float* __restrict__ root2) {
  int bx = blockIdx.x;
  int e = bx >> 3, dt = bx & 7, d0 = dt * 32;
  int tid = threadIdx.x, seg = tid >> 5, c = tid & 31;  // 8 segs x 64 k each
  __shared__ float hv[CAP][HID];
  __shared__ float red[CAP][8][32];
  for (int idx = tid; idx < CAP * HID; idx += 256) {
    int s = idx >> 9, k = idx & 511;
    hv[s][k] = hid_ws[((size_t)(e * CAP + s)) * HID + k];
  }
  __syncthreads();
  float a0 = 0.f, a1 = 0.f, a2 = 0.f, a3 = 0.f, a4 = 0.f;
  const float* W = ew2 + (size_t)e * HID * DIM + d0 + c;  // row k -> +k*DIM
  int kbase = seg * 64;
#pragma unroll
  for (int h = 0; h < 8; ++h) {
    float wv[8];
#pragma unroll
    for (int i = 0; i < 8; ++i) wv[i] = W[(size_t)(kbase + h * 8 + i) * DIM];
#pragma unroll
    for (int i = 0; i < 8; ++i) {
      int k = kbase + h * 8 + i;
      a0 = fmaf(hv[0][k], wv[i], a0);
      a1 = fmaf(hv[1][k], wv[i], a1);
      a2 = fmaf(hv[2][k], wv[i], a2);
      a3 = fmaf(hv[3][k], wv[i], a3);
      a4 = fmaf(hv[4][k], wv[i], a4);
    }
  }
  red[0][seg][c] = a0; red[1][seg][c] = a1; red[2][seg][c] = a2;
  red[3][seg][c] = a3; red[4][seg][c] = a4;
  __syncthreads();
  if (tid < CAP * 32) {
    int s = tid >> 5, cc = tid & 31;
    float sum = 0.f;
#pragma unroll
    for (int g = 0; g < 8; ++g) sum += red[s][g][cc];
    sum += eb2[e * DIM + d0 + cc];
    float w = ewt[e * CAP + s];
    if (w > 0.f)
      atomicAdd(&root2[etok[e * CAP + s] * DIM + d0 + cc], sum * w);
  }
}

// ---- logits + fused scatter: 257 blocks (one per token) x 256 threads -------
// ALL 16 batch rows per block (was 4) -> 4x less redundant hw1/hw2 traffic
// (534 -> 134 MB L2). Weights staged through a 64-row LDS tile; hrow/hid read
// as float4. Summation order per accumulator identical to the old k_table
// (k ascending, chunks of 8) -> bit-exact.
__global__ void __launch_bounds__(256) k_logits(
    const float* __restrict__ embed, const float* __restrict__ root2,
    const float* __restrict__ hw1, const float* __restrict__ hb1,
    const float* __restrict__ hw2, const float* __restrict__ hb2,
    const int* __restrict__ bidx, const int* __restrict__ boff,
    float* __restrict__ out) {
  int tok = blockIdx.x;
  int c = threadIdx.x;
  __shared__ float hrow[BB][DIM];     // 16KB
  __shared__ float wtile[64][DIM];    // 64KB staged weight tile
  __shared__ float hid[BB][DIM];      // 16KB: relu1, later the final logits
  __shared__ float tailred[BB][17];
  __shared__ float tailv[BB];
  __shared__ int tbuf[TT];            // 8KB CSR stage
  {
    float ev = embed[(size_t)tok * DIM + c];
#pragma unroll
    for (int j = 0; j < BB; ++j) hrow[j][c] = ev + root2[(size_t)j * DIM + c];
  }
  // GEMM1: col c over K=256, 16 rows, 64-row staged tiles
  float acc[BB];
#pragma unroll
  for (int r = 0; r < BB; ++r) acc[r] = hb1[c];
#pragma unroll 1
  for (int kt = 0; kt < 4; ++kt) {
    __syncthreads();   // wtile free (also covers hrow writes on kt==0)
    for (int idx = c; idx < 64 * 64; idx += 256) {     // float4 units
      int r = idx >> 6, c4 = idx & 63;
      *(float4*)&wtile[r][c4 * 4] =
          *(const float4*)&hw1[(size_t)(kt * 64 + r) * DIM + c4 * 4];
    }
    __syncthreads();
#pragma unroll 1
    for (int kb = 0; kb < 64; kb += 8) {
      int kk = kt * 64 + kb;
      float wv[8];
#pragma unroll
      for (int i = 0; i < 8; ++i) wv[i] = wtile[kb + i][c];
#pragma unroll
      for (int r = 0; r < BB; ++r) {
        float4 h0 = *(const float4*)&hrow[r][kk];
        float4 h1 = *(const float4*)&hrow[r][kk + 4];
        acc[r] = fmaf(h0.x, wv[0], acc[r]);
        acc[r] = fmaf(h0.y, wv[1], acc[r]);
        acc[r] = fmaf(h0.z, wv[2], acc[r]);
        acc[r] = fmaf(h0.w, wv[3], acc[r]);
        acc[r] = fmaf(h1.x, wv[4], acc[r]);
        acc[r] = fmaf(h1.y, wv[5], acc[r]);
        acc[r] = fmaf(h1.z, wv[6], acc[r]);
        acc[r] = fmaf(h1.w, wv[7], acc[r]);
      }
    }
  }
#pragma unroll
  for (int r = 0; r < BB; ++r) hid[r][c] = fmaxf(acc[r], 0.f);
  // GEMM2: cols 0..255 over K=256, 16 rows, staged tiles (scalar stage:
  // hw2 rows are 257 floats -> not 16B-aligned)
  float acc2[BB];
#pragma unroll
  for (int r = 0; r < BB; ++r) acc2[r] = hb2[c];
#pragma unroll 1
  for (int kt = 0; kt < 4; ++kt) {
    __syncthreads();   // wtile free (first iter also covers hid writes)
    for (int idx = c; idx < 64 * 256; idx += 256) {
      int r = idx >> 8, cc = idx & 255;
      wtile[r][cc] = hw2[(size_t)(kt * 64 + r) * VOCAB + cc];
    }
    __syncthreads();
#pragma unroll 1
    for (int kb = 0; kb < 64; kb += 8) {
      int kk = kt * 64 + kb;
      float wv[8];
#pragma unroll
      for (int i = 0; i < 8; ++i) wv[i] = wtile[kb + i][c];
#pragma unroll
      for (int r = 0; r < BB; ++r) {
        float4 h0 = *(const float4*)&hid[r][kk];
        float4 h1 = *(const float4*)&hid[r][kk + 4];
        acc2[r] = fmaf(h0.x, wv[0], acc2[r]);
        acc2[r] = fmaf(h0.y, wv[1], acc2[r]);
        acc2[r] = fmaf(h0.z, wv[2], acc2[r]);
        acc2[r] = fmaf(h0.w, wv[3], acc2[r]);
        acc2[r] = fmaf(h1.x, wv[4], acc2[r]);
        acc2[r] = fmaf(h1.y, wv[5], acc2[r]);
        acc2[r] = fmaf(h1.z, wv[6], acc2[r]);
        acc2[r] = fmaf(h1.w, wv[7], acc2[r]);
      }
    }
  }
  // tail column 256: 16 rows x 16 K-segments = all 256 threads
  {
    int r = c >> 4, seg = c & 15;
    float sum = 0.f;
#pragma unroll 4
    for (int i = 0; i < 16; ++i) {
      int k = seg * 16 + i;
      sum = fmaf(hid[r][k], hw2[(size_t)k * VOCAB + 256], sum);
    }
    tailred[r][seg] = sum;
  }
  __syncthreads();   // tailred ready; all tail reads of hid done
  if (c < BB) {
    float a = hb2[256];
#pragma unroll
    for (int s = 0; s < 16; ++s) a += tailred[c][s];
    tailv[c] = a;
  }
  // park final logits in LDS (avoids runtime-indexed reg array in scatter)
#pragma unroll
  for (int r = 0; r < BB; ++r) hid[r][c] = acc2[r];
  __syncthreads();
  // fused scatter via CSR; bidx range pre-staged to LDS per batch
#pragma unroll 1
  for (int b = 0; b < BB; ++b) {
    int s = boff[b * (VOCAB + 1) + tok];
    int e = boff[b * (VOCAB + 1) + tok + 1];
    int n = e - s;
    __syncthreads();   // tbuf free from previous batch
    for (int m = c; m < n; m += 256) tbuf[m] = bidx[b * TT + s + m];
    __syncthreads();
    float aj = hid[b][c];
    float tl = tailv[b];
#pragma unroll 1
    for (int m = 0; m < n; ++m) {
      int t = tbuf[m];
      size_t base = (size_t)(b * TT + t) * VOCAB;
      out[base + c] = aj;
      if (c == 0) out[base + 256] = tl;
    }
  }
}

extern "C" void kernel_launch(void* const* d_in, const int* in_sizes, int n_in,
                              void* d_out, int out_size, void* d_ws, size_t ws_size,
                              hipStream_t stream) {
  (void)in_sizes; (void)n_in; (void)out_size; (void)ws_size;
  const int*   tokens     = (const int*)d_in[0];
  const float* embed      = (const float*)d_in[1];
  const float* pin_w      = (const float*)d_in[2];
  const float* pin_b      = (const float*)d_in[3];
  const float* pch_w      = (const float*)d_in[4];
  const float* pch_b      = (const float*)d_in[5];
  const float* depth_bias = (const float*)d_in[6];
  // d_in[7..10] = q_w,q_b,k_w,k_b: provably unused (uniform softmax)
  const float* v_w        = (const float*)d_in[11];
  const float* v_b        = (const float*)d_in[12];
  const float* o_w        = (const float*)d_in[13];
  const float* o_b        = (const float*)d_in[14];
  const float* level_gate = (const float*)d_in[15];
  const float* depth_gate = (const float*)d_in[16];
  const float* in_proj_w  = (const float*)d_in[17];
  const float* in_proj_b  = (const float*)d_in[18];
  const float* out_proj_w = (const float*)d_in[19];
  const float* out_proj_b = (const float*)d_in[20];
  const float* ln_g       = (const float*)d_in[21];
  const float* ln_b       = (const float*)d_in[22];
  const float* ic_gate    = (const float*)d_in[23];
  const float* gate_w     = (const float*)d_in[24];
  const float* gate_b     = (const float*)d_in[25];
  const float* ew1        = (const float*)d_in[26];
  const float* eb1        = (const float*)d_in[27];
  const float* ew2        = (const float*)d_in[28];
  const float* eb2        = (const float*)d_in[29];
  const float* hw1        = (const float*)d_in[30];
  const float* hb1        = (const float*)d_in[31];
  const float* hw2        = (const float*)d_in[32];
  const float* hb2        = (const float*)d_in[33];
  float* out = (float*)d_out;

  float* ws      = (float*)d_ws;
  float* rootA   = ws + 4096;            // 4096 floats
  float* root2   = ws + 8192;            // 4096 floats
  int*   etok    = (int*)(ws + 22528);   // 40
  float* ewt     = ws + 22576;           // 40
  float* hid_ws  = ws + 22656;           // 8*5*512 = 20480 floats
  int*   bidx    = (int*)(ws + 43136);   // 16*2048 = 32768 ints
  int*   boff    = (int*)(ws + 75904);   // 16*258  =  4128 ints

  k_fractal<<<BB, 1024, 0, stream>>>(tokens, embed, pin_w, pin_b, pch_w, pch_b,
                                     depth_bias, v_w, v_b, o_w, o_b, level_gate,
                                     depth_gate, in_proj_w, in_proj_b, out_proj_w,
                                     out_proj_b, ln_g, ln_b, ic_gate, rootA, root2,
                                     bidx, boff);
  k_expert1<<<NEXP * 8, 256, 0, stream>>>(rootA, gate_w, gate_b, ew1, eb1,
                                          etok, ewt, hid_ws);
  k_expert2<<<NEXP * 8, 256, 0, stream>>>(hid_ws, ew2, eb2, ewt, etok, root2);
  k_logits<<<VOCAB, 256, 0, stream>>>(embed, root2, hw1, hb1, hw2, hb2,
                                      bidx, boff, out);
}

// Round 7
// 244.323 us; speedup vs baseline: 1.6241x; 1.6241x over previous
//
#include <hip/hip_runtime.h>
#include <hip/hip_bf16.h>
#include <math.h>

#define DIM    256
#define DEPTH  5
#define FANOUT 10
#define VOCAB  257
#define BB     16
#define TT     2048
#define NEXP   8
#define HID    512
#define TOPK   2
#define CAP    5   // ceil(16*2/8*1.1)

__device__ __forceinline__ float sigm(float x) { return 1.f / (1.f + expf(-x)); }

// 256x256 matvec partial: 1024 threads = 16 ksegs x 64 col-quads.
// Depth-8 float4 batches inside a KEPT loop (#pragma unroll 1): 2 latency
// exposures per matvec. R1-R3 lesson: fully-unrolled forms get ALL loads
// hoisted and spill 10MB/dispatch; only a real loop boundary stops the hoist.
__device__ __forceinline__ void mv8x2(const float* sv, const float* __restrict__ W,
                                      int kseg, int cq, float red[16][DIM]) {
  const float* Wp = W + (size_t)kseg * 16 * DIM + cq * 4;
  float4 acc = {0.f, 0.f, 0.f, 0.f};
#pragma unroll 1
  for (int h = 0; h < 2; ++h) {
    float4 wv[8];
#pragma unroll
    for (int i = 0; i < 8; ++i)
      wv[i] = *(const float4*)(Wp + (size_t)(h * 8 + i) * DIM);
#pragma unroll
    for (int i = 0; i < 8; ++i) {
      float s = sv[kseg * 16 + h * 8 + i];
      acc.x = fmaf(s, wv[i].x, acc.x);
      acc.y = fmaf(s, wv[i].y, acc.y);
      acc.z = fmaf(s, wv[i].z, acc.z);
      acc.w = fmaf(s, wv[i].w, acc.w);
    }
    __builtin_amdgcn_sched_barrier(0);
  }
  *(float4*)&red[kseg][cq * 4] = acc;
}

__device__ __forceinline__ float sum16(const float red[16][DIM], int d) {
  float s = 0.f;
#pragma unroll
  for (int g = 0; g < 16; ++g) s += red[g][d];
  return s;
}

// ------ collapsed fractal + context + root2 init + token-CSR build -----------
__global__ void __launch_bounds__(1024) k_fractal(
    const int* __restrict__ tokens, const float* __restrict__ embed,
    const float* __restrict__ pin_w, const float* __restrict__ pin_b,
    const float* __restrict__ pch_w, const float* __restrict__ pch_b,
    const float* __restrict__ depth_bias,
    const float* __restrict__ v_w, const float* __restrict__ v_b,
    const float* __restrict__ o_w, const float* __restrict__ o_b,
    const float* __restrict__ level_gate, const float* __restrict__ depth_gate,
    const float* __restrict__ in_proj_w, const float* __restrict__ in_proj_b,
    const float* __restrict__ out_proj_w, const float* __restrict__ out_proj_b,
    const float* __restrict__ ln_g, const float* __restrict__ ln_b,
    const float* __restrict__ ic_gate,
    float* __restrict__ rootA, float* __restrict__ root2,
    int* __restrict__ bidx, int* __restrict__ boff) {
  int b = blockIdx.x;
  int tid = threadIdx.x;
  int d = tid & 255;
  int ks = tid >> 8;       // 0..3 (consumer / in_proj layout)
  int k0 = ks * 64;
  int kseg = tid >> 6;     // 0..15 (mv8x2 layout)
  int cq = tid & 63;
  __shared__ int cnt[VOCAB];
  __shared__ float sv[DIM];
  __shared__ float basev[DIM];
  __shared__ float ym[DEPTH][DIM];
  __shared__ float q0v[DIM], kh[DEPTH][DIM], vh[DEPTH][DIM];
  __shared__ float red11[4][11][DIM];   // in_proj reduction; also aliases red16
  __shared__ float zsv[DIM];
  __shared__ float aw[16];
  __shared__ float redl[8];
  __shared__ int offb[VOCAB + 1];
  __shared__ int woff[VOCAB];
  float (*red16)[DIM] = reinterpret_cast<float(*)[DIM]>(&red11[0][0][0]); // 16KB of 44KB

  // ---- context = (histogram @ embed) / T, branch-free ----
  for (int i = tid; i < VOCAB; i += 1024) cnt[i] = 0;
  __syncthreads();
  for (int t = tid; t < TT; t += 1024) atomicAdd(&cnt[tokens[b * TT + t]], 1);
  __syncthreads();
  {
    const float* Ep = embed + (size_t)kseg * 16 * DIM + cq * 4;
    float4 acc = {0.f, 0.f, 0.f, 0.f};
#pragma unroll 1
    for (int h = 0; h < 2; ++h) {
      float4 ev[8];
#pragma unroll
      for (int i = 0; i < 8; ++i)
        ev[i] = *(const float4*)(Ep + (size_t)(h * 8 + i) * DIM);
#pragma unroll
      for (int i = 0; i < 8; ++i) {
        float cv = (float)cnt[kseg * 16 + h * 8 + i];
        acc.x = fmaf(cv, ev[i].x, acc.x);
        acc.y = fmaf(cv, ev[i].y, acc.y);
        acc.z = fmaf(cv, ev[i].z, acc.z);
        acc.w = fmaf(cv, ev[i].w, acc.w);
      }
      __builtin_amdgcn_sched_barrier(0);
    }
    *(float4*)&red16[kseg][cq * 4] = acc;
  }
  __syncthreads();
  if (ks == 0) {
    float s = sum16(red16, d);
    s = fmaf((float)cnt[256], embed[(size_t)256 * DIM + d], s);
    sv[d] = s * (1.0f / (float)TT);
  }
  __syncthreads();

  mv8x2(sv, pin_w, kseg, cq, red16);
  __syncthreads();
  if (ks == 0) {
    float base = sum16(red16, d) + pin_b[d];
    basev[d] = base;
    float u = (base + depth_bias[4 * DIM + d] + pch_b[d]) * sigm(level_gate[4]);
    sv[d] = fmaxf(u, 0.f);
  }
  __syncthreads();
  mv8x2(sv, o_w, kseg, cq, red16);
  __syncthreads();
  if (ks == 0) {
    float y = sum16(red16, d) + o_b[d];
    ym[4][d] = y;
    sv[d] = y;
  }
  __syncthreads();
  for (int l = 3; l >= 0; --l) {
    mv8x2(sv, v_w, kseg, cq, red16);
    __syncthreads();
    if (ks == 0) {
      float vv = sum16(red16, d) + v_b[d];
      sv[d] = sigm(depth_gate[l * DIM + d]) * vv;   // uniform softmax -> child = v
    }
    __syncthreads();
    mv8x2(sv, pch_w, kseg, cq, red16);
    __syncthreads();
    if (ks == 0) {
      float t = sum16(red16, d) + pch_b[d];
      float u = (basev[d] + depth_bias[l * DIM + d] + t) * sigm(level_gate[l]);
      sv[d] = fmaxf(u, 0.f);
    }
    __syncthreads();
    mv8x2(sv, o_w, kseg, cq, red16);
    __syncthreads();
    if (ks == 0) {
      float y = sum16(red16, d) + o_b[d];
      ym[l][d] = y;
      sv[d] = y;
    }
    __syncthreads();
  }
  // ---- in_proj, ALL levels in ONE pass over the weights (8-deep batches) ----
  {
    float aq = 0.f;
    float ak0 = 0.f, ak1 = 0.f, ak2 = 0.f, ak3 = 0.f, ak4 = 0.f;
    float av0 = 0.f, av1 = 0.f, av2 = 0.f, av3 = 0.f, av4 = 0.f;
#pragma unroll
    for (int h = 0; h < 8; ++h) {
      int kb = k0 + h * 8;
      float wq[8], wk[8], wv8[8];
#pragma unroll
      for (int i = 0; i < 8; ++i) {
        const float* wrow = in_proj_w + (size_t)(kb + i) * 768;
        wq[i] = wrow[d]; wk[i] = wrow[256 + d]; wv8[i] = wrow[512 + d];
      }
#pragma unroll
      for (int i = 0; i < 8; ++i) {
        float z0 = ym[0][kb + i];
        aq  = fmaf(z0, wq[i], aq);
        ak0 = fmaf(z0, wk[i], ak0);
        av0 = fmaf(z0, wv8[i], av0);
        float z1 = ym[1][kb + i];
        ak1 = fmaf(z1, wk[i], ak1);
        av1 = fmaf(z1, wv8[i], av1);
        float z2 = ym[2][kb + i];
        ak2 = fmaf(z2, wk[i], ak2);
        av2 = fmaf(z2, wv8[i], av2);
        float z3 = ym[3][kb + i];
        ak3 = fmaf(z3, wk[i], ak3);
        av3 = fmaf(z3, wv8[i], av3);
        float z4 = ym[4][kb + i];
        ak4 = fmaf(z4, wk[i], ak4);
        av4 = fmaf(z4, wv8[i], av4);
      }
    }
    red11[ks][0][d] = ak0; red11[ks][1][d] = ak1; red11[ks][2][d] = ak2;
    red11[ks][3][d] = ak3; red11[ks][4][d] = ak4;
    red11[ks][5][d] = av0; red11[ks][6][d] = av1; red11[ks][7][d] = av2;
    red11[ks][8][d] = av3; red11[ks][9][d] = av4;
    red11[ks][10][d] = aq;
  }
  __syncthreads();
  for (int idx = tid; idx < 11 * DIM; idx += 1024) {
    int c = idx >> 8, dd = idx & 255;
    float sum = red11[0][c][dd] + red11[1][c][dd] + red11[2][c][dd] + red11[3][c][dd];
    if (c < 5)       kh[c][dd]     = sum + in_proj_b[256 + dd];
    else if (c < 10) vh[c - 5][dd] = sum + in_proj_b[512 + dd];
    else             q0v[dd]       = sum + in_proj_b[dd];
  }
  __syncthreads();
  {
    int wid = tid >> 6;
    if (wid < 10) {
      int h = wid / 5, l = wid - h * 5;
      int lane = tid & 63;
      float s = q0v[h * 128 + lane] * kh[l][h * 128 + lane];
      s = fmaf(q0v[h * 128 + 64 + lane], kh[l][h * 128 + 64 + lane], s);
      for (int o = 32; o > 0; o >>= 1) s += __shfl_down(s, o, 64);
      if (lane == 0) aw[wid] = s * 0.08838834764831845f;  // 1/sqrt(128)
    }
  }
  __syncthreads();
  if (tid < 2) {
    float m = aw[tid * 5];
    for (int l = 1; l < 5; ++l) m = fmaxf(m, aw[tid * 5 + l]);
    float e[5], ssum = 0.f;
    for (int l = 0; l < 5; ++l) { e[l] = expf(aw[tid * 5 + l] - m); ssum += e[l]; }
    for (int l = 0; l < 5; ++l) aw[tid * 5 + l] = e[l] / ssum;
  }
  __syncthreads();
  if (ks == 0) {
    int h = d >> 7;
    float z2 = 0.f;
    for (int l = 0; l < 5; ++l) z2 = fmaf(aw[h * 5 + l], vh[l][d], z2);
    sv[d] = z2;
  }
  __syncthreads();
  mv8x2(sv, out_proj_w, kseg, cq, red16);
  __syncthreads();
  if (ks == 0) {
    float z2p = sum16(red16, d) + out_proj_b[d];
    zsv[d] = ym[0][d] + z2p;
  }
  __syncthreads();
  float zs = 0.f, df = 0.f, mu = 0.f;
  if (tid < 256) {
    zs = zsv[tid];
    float v = zs;
    for (int o = 32; o > 0; o >>= 1) v += __shfl_down(v, o, 64);
    if ((tid & 63) == 0) redl[tid >> 6] = v;
  }
  __syncthreads();
  if (tid < 256) {
    mu = (redl[0] + redl[1] + redl[2] + redl[3]) * (1.f / 256.f);
    df = zs - mu;
  }
  __syncthreads();
  if (tid < 256) {
    float v = df * df;
    for (int o = 32; o > 0; o >>= 1) v += __shfl_down(v, o, 64);
    if ((tid & 63) == 0) redl[tid >> 6] = v;
  }
  __syncthreads();
  if (tid < 256) {
    float var = (redl[0] + redl[1] + redl[2] + redl[3]) * (1.f / 256.f);
    float zn = df / sqrtf(var + 1e-5f) * ln_g[tid] + ln_b[tid];
    float r = ym[0][tid] + sigm(ic_gate[0]) * zn;
    rootA[b * DIM + tid] = r;
    root2[b * DIM + tid] = r;   // experts atomically add on top
  }
  // ---- token CSR for fused logits-scatter ----
  __syncthreads();
  if (tid == 0) {
    int a = 0;
    for (int v = 0; v < VOCAB; ++v) { offb[v] = a; a += cnt[v]; }
    offb[VOCAB] = a;              // == TT
  }
  __syncthreads();
  if (tid <= VOCAB) boff[b * (VOCAB + 1) + tid] = offb[tid];
  if (tid < VOCAB) woff[tid] = offb[tid];
  __syncthreads();
  for (int t = tid; t < TT; t += 1024) {
    int tok = tokens[b * TT + t];
    int p = atomicAdd(&woff[tok], 1);
    bidx[b * TT + p] = t;         // bucket order arbitrary; output order-invariant
  }
}

// ---- fused MoE: gating + GEMM1 + partial-GEMM2 + combine -------------------
// 64 blocks = 8 experts x 8 tiles of 64 HID cols. Each block: gating (LDS-
// staged, bit-exact order), its 64-col hid slice, then the PARTIAL GEMM2 over
// those 64 K atomically added into root2 (jt==0 adds eb2). Kills k_expert2's
// launch + the hid_ws global round-trip. Per-64-chunk summation order matches
// the old per-seg order; only the final 8-way combine becomes atomic-order
// (the old kernel already combined (expert,token) contributions atomically).
__global__ void __launch_bounds__(256) k_moe(
    const float* __restrict__ rootA,
    const float* __restrict__ gate_w, const float* __restrict__ gate_b,
    const float* __restrict__ ew1, const float* __restrict__ eb1,
    const float* __restrict__ ew2, const float* __restrict__ eb2,
    float* __restrict__ root2) {
  int bx = blockIdx.x;
  int e = bx >> 3, jt = bx & 7, j0 = jt * 64;
  int tid = threadIdx.x, w = tid >> 6, lane = tid & 63;
  __shared__ float rlds[BB * DIM];      // 16KB rootA copy
  __shared__ float gwlds[DIM * NEXP];   // 8KB gate_w copy
  __shared__ float xin[CAP][DIM];
  __shared__ float red[CAP][4][64];
  __shared__ float hloc[CAP][64];
  __shared__ float sc[BB * NEXP];
  __shared__ float gs[BB * TOPK];
  __shared__ int gidx[BB * TOPK];
  __shared__ int stok[CAP];
  __shared__ float swt[CAP];
  for (int idx = tid; idx < BB * DIM / 4; idx += 256)
    *(float4*)&rlds[idx * 4] = *(const float4*)&rootA[idx * 4];
  for (int idx = tid; idx < DIM * NEXP / 4; idx += 256)
    *(float4*)&gwlds[idx * 4] = *(const float4*)&gate_w[idx * 4];
  __syncthreads();
  if (tid < BB * NEXP) {
    int b = tid >> 3, ep = tid & 7;
    float chunk[8];
#pragma unroll
    for (int g = 0; g < 8; ++g) {
      float acc = 0.f;
#pragma unroll 8
      for (int i = 0; i < 32; ++i) {
        int k = g * 32 + i;
        acc = fmaf(rlds[b * DIM + k], gwlds[k * NEXP + ep], acc);
      }
      chunk[g] = acc;
    }
    float s = gate_b[ep];
#pragma unroll
    for (int g = 0; g < 8; ++g) s += chunk[g];
    sc[tid] = s;
  }
  __syncthreads();
  if (tid < BB) {  // top-2 + softmax per batch (identical order to old k_gate)
    int bb = tid;
    int i0 = 0; float v0 = sc[bb * 8 + 0];
    for (int ee = 1; ee < 8; ++ee) { float v = sc[bb * 8 + ee]; if (v > v0) { v0 = v; i0 = ee; } }
    int i1 = -1; float v1 = -1e30f;
    for (int ee = 0; ee < 8; ++ee) {
      if (ee == i0) continue;
      float v = sc[bb * 8 + ee];
      if (v > v1) { v1 = v; i1 = ee; }
    }
    float e1v = expf(v1 - v0);
    float s = 1.f + e1v;
    gs[bb * 2 + 0] = 1.f / s;  gidx[bb * 2 + 0] = i0;
    gs[bb * 2 + 1] = e1v / s;  gidx[bb * 2 + 1] = i1;
  }
  __syncthreads();
  if (tid == 0) {  // top-CAP for own expert: bitmask, value desc / index asc
    unsigned used = 0u;
    for (int s = 0; s < CAP; ++s) {
      int bi = 0; float bv = -1e30f;
      for (int i = 0; i < 32; ++i) {
        if (used & (1u << i)) continue;
        float v = (gidx[i] == e) ? gs[i] : -1.0f;
        if (v > bv) { bv = v; bi = i; }
      }
      used |= (1u << bi);
      stok[s] = bi >> 1;
      swt[s] = bv > 0.f ? bv : 0.f;
    }
  }
  __syncthreads();
  for (int idx = tid; idx < CAP * DIM; idx += 256) {
    int s = idx >> 8, k = idx & 255;
    xin[s][k] = rlds[stok[s] * DIM + k];
  }
  __syncthreads();
  // GEMM1: this block's 64 HID cols (identical order to old k_expert1)
  {
    float a0 = 0.f, a1 = 0.f, a2 = 0.f, a3 = 0.f, a4 = 0.f;
    const float* W = ew1 + (size_t)e * DIM * HID + j0 + lane;  // row k -> +k*HID
    int kbase = w * 64;
#pragma unroll
    for (int h = 0; h < 8; ++h) {
      float wv[8];
#pragma unroll
      for (int i = 0; i < 8; ++i) wv[i] = W[(size_t)(kbase + h * 8 + i) * HID];
#pragma unroll
      for (int i = 0; i < 8; ++i) {
        int k = kbase + h * 8 + i;
        a0 = fmaf(xin[0][k], wv[i], a0);
        a1 = fmaf(xin[1][k], wv[i], a1);
        a2 = fmaf(xin[2][k], wv[i], a2);
        a3 = fmaf(xin[3][k], wv[i], a3);
        a4 = fmaf(xin[4][k], wv[i], a4);
      }
    }
    red[0][w][lane] = a0; red[1][w][lane] = a1; red[2][w][lane] = a2;
    red[3][w][lane] = a3; red[4][w][lane] = a4;
  }
  __syncthreads();
  for (int idx = tid; idx < CAP * 64; idx += 256) {
    int s = idx >> 6, j = idx & 63;
    float sum = red[s][0][j] + red[s][1][j] + red[s][2][j] + red[s][3][j]
              + eb1[e * HID + j0 + j];
    hloc[s][j] = fmaxf(sum, 0.f);
  }
  __syncthreads();
  // partial GEMM2: K = this block's 64 hid cols, d = tid (0..255)
  {
    int d = tid;
    float a0 = 0.f, a1 = 0.f, a2 = 0.f, a3 = 0.f, a4 = 0.f;
    const float* W2 = ew2 + (size_t)e * HID * DIM + (size_t)j0 * DIM + d;
#pragma unroll
    for (int h = 0; h < 8; ++h) {
      float wv[8];
#pragma unroll
      for (int i = 0; i < 8; ++i) wv[i] = W2[(size_t)(h * 8 + i) * DIM];
#pragma unroll
      for (int i = 0; i < 8; ++i) {
        int j = h * 8 + i;
        a0 = fmaf(hloc[0][j], wv[i], a0);
        a1 = fmaf(hloc[1][j], wv[i], a1);
        a2 = fmaf(hloc[2][j], wv[i], a2);
        a3 = fmaf(hloc[3][j], wv[i], a3);
        a4 = fmaf(hloc[4][j], wv[i], a4);
      }
    }
    float bias = (jt == 0) ? eb2[e * DIM + d] : 0.f;
    float pa[1];
    (void)pa;
#pragma unroll
    for (int s = 0; s < CAP; ++s) {
      float as = (s == 0) ? a0 : (s == 1) ? a1 : (s == 2) ? a2 : (s == 3) ? a3 : a4;
      float wgt = swt[s];
      if (wgt > 0.f)
        atomicAdd(&root2[stok[s] * DIM + d], (as + bias) * wgt);
    }
  }
}

// ---- logits + fused scatter: grid (257 tokens x 4 rowgroups) x 256 threads --
// R5-proven shape: 1028 blocks keeps the machine latency-tolerant; weights
// (520KB) are L2-resident so redundant reads are cheap. (R6's 16-row/257-block
// variant: 1 block/CU, serial chain 4x longer -> 205us. Reverted.)
__global__ void __launch_bounds__(256) k_logits(
    const float* __restrict__ embed, const float* __restrict__ root2,
    const float* __restrict__ hw1, const float* __restrict__ hb1,
    const float* __restrict__ hw2, const float* __restrict__ hb2,
    const int* __restrict__ bidx, const int* __restrict__ boff,
    float* __restrict__ out) {
  int tok = blockIdx.x, r0 = blockIdx.y * 4;
  int c = threadIdx.x;
  __shared__ float hrow[4][DIM];
  __shared__ float hid[4][DIM];
  __shared__ float tailred[4][17];
  __shared__ float tailv[4];
  {
    float ev = embed[(size_t)tok * DIM + c];
#pragma unroll
    for (int j = 0; j < 4; ++j) hrow[j][c] = ev + root2[(size_t)(r0 + j) * DIM + c];
  }
  __syncthreads();
  // GEMM1: col c over K=256, 4 rows
  {
    float a0 = hb1[c], a1 = a0, a2 = a0, a3 = a0;
    for (int kb = 0; kb < DIM; kb += 8) {
      float wv[8];
#pragma unroll
      for (int i = 0; i < 8; ++i) wv[i] = hw1[(size_t)(kb + i) * DIM + c];
#pragma unroll
      for (int i = 0; i < 8; ++i) {
        int k = kb + i;
        a0 = fmaf(hrow[0][k], wv[i], a0);
        a1 = fmaf(hrow[1][k], wv[i], a1);
        a2 = fmaf(hrow[2][k], wv[i], a2);
        a3 = fmaf(hrow[3][k], wv[i], a3);
      }
    }
    hid[0][c] = fmaxf(a0, 0.f); hid[1][c] = fmaxf(a1, 0.f);
    hid[2][c] = fmaxf(a2, 0.f); hid[3][c] = fmaxf(a3, 0.f);
  }
  __syncthreads();
  // GEMM2: cols 0..255 into registers
  float a0, a1, a2, a3;
  {
    a0 = hb2[c]; a1 = a0; a2 = a0; a3 = a0;
    for (int kb = 0; kb < DIM; kb += 8) {
      float wv[8];
#pragma unroll
      for (int i = 0; i < 8; ++i) wv[i] = hw2[(size_t)(kb + i) * VOCAB + c];
#pragma unroll
      for (int i = 0; i < 8; ++i) {
        int k = kb + i;
        a0 = fmaf(hid[0][k], wv[i], a0);
        a1 = fmaf(hid[1][k], wv[i], a1);
        a2 = fmaf(hid[2][k], wv[i], a2);
        a3 = fmaf(hid[3][k], wv[i], a3);
      }
    }
  }
  // tail column 256: 16-way K-split across first 64 threads
  if (c < 64) {
    int r = c >> 4, seg = c & 15;
    float sum = 0.f;
#pragma unroll 4
    for (int i = 0; i < 16; ++i) {
      int k = seg * 16 + i;
      sum = fmaf(hid[r][k], hw2[(size_t)k * VOCAB + 256], sum);
    }
    tailred[r][seg] = sum;
  }
  __syncthreads();
  if (c < 4) {
    float a = hb2[256];
#pragma unroll
    for (int s = 0; s < 16; ++s) a += tailred[c][s];
    tailv[c] = a;
  }
  __syncthreads();
  // fused scatter: write this row to every matching t (coalesced 1KB rows)
#pragma unroll
  for (int j = 0; j < 4; ++j) {
    int b = r0 + j;
    int s = boff[b * (VOCAB + 1) + tok];
    int e = boff[b * (VOCAB + 1) + tok + 1];
    float aj = (j == 0) ? a0 : (j == 1) ? a1 : (j == 2) ? a2 : a3;
    float tl = tailv[j];
    for (int m = s; m < e; ++m) {
      int t = bidx[b * TT + m];
      size_t base = (size_t)(b * TT + t) * VOCAB;
      out[base + c] = aj;
      if (c == 0) out[base + 256] = tl;
    }
  }
}

extern "C" void kernel_launch(void* const* d_in, const int* in_sizes, int n_in,
                              void* d_out, int out_size, void* d_ws, size_t ws_size,
                              hipStream_t stream) {
  (void)in_sizes; (void)n_in; (void)out_size; (void)ws_size;
  const int*   tokens     = (const int*)d_in[0];
  const float* embed      = (const float*)d_in[1];
  const float* pin_w      = (const float*)d_in[2];
  const float* pin_b      = (const float*)d_in[3];
  const float* pch_w      = (const float*)d_in[4];
  const float* pch_b      = (const float*)d_in[5];
  const float* depth_bias = (const float*)d_in[6];
  // d_in[7..10] = q_w,q_b,k_w,k_b: provably unused (uniform softmax)
  const float* v_w        = (const float*)d_in[11];
  const float* v_b        = (const float*)d_in[12];
  const float* o_w        = (const float*)d_in[13];
  const float* o_b        = (const float*)d_in[14];
  const float* level_gate = (const float*)d_in[15];
  const float* depth_gate = (const float*)d_in[16];
  const float* in_proj_w  = (const float*)d_in[17];
  const float* in_proj_b  = (const float*)d_in[18];
  const float* out_proj_w = (const float*)d_in[19];
  const float* out_proj_b = (const float*)d_in[20];
  const float* ln_g       = (const float*)d_in[21];
  const float* ln_b       = (const float*)d_in[22];
  const float* ic_gate    = (const float*)d_in[23];
  const float* gate_w     = (const float*)d_in[24];
  const float* gate_b     = (const float*)d_in[25];
  const float* ew1        = (const float*)d_in[26];
  const float* eb1        = (const float*)d_in[27];
  const float* ew2        = (const float*)d_in[28];
  const float* eb2        = (const float*)d_in[29];
  const float* hw1        = (const float*)d_in[30];
  const float* hb1        = (const float*)d_in[31];
  const float* hw2        = (const float*)d_in[32];
  const float* hb2        = (const float*)d_in[33];
  float* out = (float*)d_out;

  float* ws      = (float*)d_ws;
  float* rootA   = ws + 4096;            // 4096 floats
  float* root2   = ws + 8192;            // 4096 floats
  int*   bidx    = (int*)(ws + 43136);   // 16*2048 = 32768 ints
  int*   boff    = (int*)(ws + 75904);   // 16*258  =  4128 ints

  k_fractal<<<BB, 1024, 0, stream>>>(tokens, embed, pin_w, pin_b, pch_w, pch_b,
                                     depth_bias, v_w, v_b, o_w, o_b, level_gate,
                                     depth_gate, in_proj_w, in_proj_b, out_proj_w,
                                     out_proj_b, ln_g, ln_b, ic_gate, rootA, root2,
                                     bidx, boff);
  k_moe<<<NEXP * 8, 256, 0, stream>>>(rootA, gate_w, gate_b, ew1, eb1,
                                      ew2, eb2, root2);
  k_logits<<<dim3(VOCAB, 4), 256, 0, stream>>>(embed, root2, hw1, hb1, hw2, hb2,
                                               bidx, boff, out);
}

// Round 8
// 234.252 us; speedup vs baseline: 1.6939x; 1.0430x over previous
//
#include <hip/hip_runtime.h>
#include <hip/hip_bf16.h>
#include <math.h>

#define DIM    256
#define DEPTH  5
#define FANOUT 10
#define VOCAB  257
#define BB     16
#define TT     2048
#define NEXP   8
#define HID    512
#define TOPK   2
#define CAP    5   // ceil(16*2/8*1.1)

__device__ __forceinline__ float sigm(float x) { return 1.f / (1.f + expf(-x)); }

// 256x256 matvec partial: 1024 threads = 16 ksegs x 64 col-quads.
// Depth-8 float4 batches inside a KEPT loop (#pragma unroll 1): 2 latency
// exposures per matvec. R1-R3 lesson: fully-unrolled forms get ALL loads
// hoisted and spill 10MB/dispatch; only a real loop boundary stops the hoist.
__device__ __forceinline__ void mv8x2(const float* sv, const float* __restrict__ W,
                                      int kseg, int cq, float red[16][DIM]) {
  const float* Wp = W + (size_t)kseg * 16 * DIM + cq * 4;
  float4 acc = {0.f, 0.f, 0.f, 0.f};
#pragma unroll 1
  for (int h = 0; h < 2; ++h) {
    float4 wv[8];
#pragma unroll
    for (int i = 0; i < 8; ++i)
      wv[i] = *(const float4*)(Wp + (size_t)(h * 8 + i) * DIM);
#pragma unroll
    for (int i = 0; i < 8; ++i) {
      float s = sv[kseg * 16 + h * 8 + i];
      acc.x = fmaf(s, wv[i].x, acc.x);
      acc.y = fmaf(s, wv[i].y, acc.y);
      acc.z = fmaf(s, wv[i].z, acc.z);
      acc.w = fmaf(s, wv[i].w, acc.w);
    }
    __builtin_amdgcn_sched_barrier(0);
  }
  *(float4*)&red[kseg][cq * 4] = acc;
}

__device__ __forceinline__ float sum16(const float red[16][DIM], int d) {
  float s = 0.f;
#pragma unroll
  for (int g = 0; g < 16; ++g) s += red[g][d];
  return s;
}

// ------ collapsed fractal + context + root2 init ------------------------------
// Grid = 256 blocks:
//   0..15    : the 16 real per-batch fractal chains (unchanged arithmetic)
//   16..31   : token-CSR build for batch (bx-16)  [depends only on tokens]
//   32..255  : L2/L3 warm-up streamers for the weight set (keep-alive reads).
// Rationale (R7 counters): k_fractal runs at dur ~= FETCH/140GB/s -- a cold-
// fetch latency chain; k_logits' 533MB L2 sweep evicts the 2.3MB weight set
// every iteration. 240 idle CUs re-warm L2/L3 while real blocks do histogram.
__global__ void __launch_bounds__(1024) k_fractal(
    const int* __restrict__ tokens, const float* __restrict__ embed,
    const float* __restrict__ pin_w, const float* __restrict__ pin_b,
    const float* __restrict__ pch_w, const float* __restrict__ pch_b,
    const float* __restrict__ depth_bias,
    const float* __restrict__ v_w, const float* __restrict__ v_b,
    const float* __restrict__ o_w, const float* __restrict__ o_b,
    const float* __restrict__ level_gate, const float* __restrict__ depth_gate,
    const float* __restrict__ in_proj_w, const float* __restrict__ in_proj_b,
    const float* __restrict__ out_proj_w, const float* __restrict__ out_proj_b,
    const float* __restrict__ ln_g, const float* __restrict__ ln_b,
    const float* __restrict__ ic_gate,
    float* __restrict__ rootA, float* __restrict__ root2,
    int* __restrict__ bidx, int* __restrict__ boff) {
  int bx = blockIdx.x;
  int tid = threadIdx.x;
  __shared__ int cnt[VOCAB];
  __shared__ float sv[DIM];
  __shared__ float basev[DIM];
  __shared__ float ym[DEPTH][DIM];
  __shared__ float q0v[DIM], kh[DEPTH][DIM], vh[DEPTH][DIM];
  __shared__ float red11[4][11][DIM];   // in_proj reduction; also aliases red16
  __shared__ float zsv[DIM];
  __shared__ float aw[16];
  __shared__ float redl[8];
  __shared__ int offb[VOCAB + 1];
  __shared__ int woff[VOCAB];
  float (*red16)[DIM] = reinterpret_cast<float(*)[DIM]>(&red11[0][0][0]); // 16KB of 44KB

  if (bx >= 2 * BB) {
    // ---- warm-up streamer: one 64KB region of the weight set ----
    // 36 regions x 16384 floats: pin(4) pch(4) v(4) o(4) out_proj(4)
    // in_proj(12) embed(4). region = (q + xcd-residue) % 36 so each XCD's L2
    // covers 28/36 regions and L3 covers all.
    int p = bx - 2 * BB;              // 0..223
    int r = ((p >> 3) + (bx & 7)) % 36;
    const float* W; size_t off;
    if (r < 4)       { W = pin_w;      off = (size_t)r * 16384; }
    else if (r < 8)  { W = pch_w;      off = (size_t)(r - 4) * 16384; }
    else if (r < 12) { W = v_w;        off = (size_t)(r - 8) * 16384; }
    else if (r < 16) { W = o_w;        off = (size_t)(r - 12) * 16384; }
    else if (r < 20) { W = out_proj_w; off = (size_t)(r - 16) * 16384; }
    else if (r < 32) { W = in_proj_w;  off = (size_t)(r - 20) * 16384; }
    else             { W = embed;      off = (size_t)(r - 32) * 16384; }
    const float4* src = (const float4*)(W + off) + tid;
    float4 a = src[0], b4 = src[1024], c4 = src[2048], d4 = src[3072];
    float sx = a.x + b4.x + c4.x + d4.x;
    float sy = a.y + b4.y + c4.y + d4.y;
    float sz = a.z + b4.z + c4.z + d4.z;
    float sw = a.w + b4.w + c4.w + d4.w;
    asm volatile("" :: "v"(sx), "v"(sy), "v"(sz), "v"(sw));
    return;
  }
  if (bx >= BB) {
    // ---- token CSR for batch b: independent of the chain, off critical path --
    int b = bx - BB;
    for (int i = tid; i < VOCAB; i += 1024) cnt[i] = 0;
    __syncthreads();
    for (int t = tid; t < TT; t += 1024) atomicAdd(&cnt[tokens[b * TT + t]], 1);
    __syncthreads();
    if (tid == 0) {
      int a = 0;
      for (int v = 0; v < VOCAB; ++v) { offb[v] = a; a += cnt[v]; }
      offb[VOCAB] = a;              // == TT
    }
    __syncthreads();
    if (tid <= VOCAB) boff[b * (VOCAB + 1) + tid] = offb[tid];
    if (tid < VOCAB) woff[tid] = offb[tid];
    __syncthreads();
    for (int t = tid; t < TT; t += 1024) {
      int tok = tokens[b * TT + t];
      int p = atomicAdd(&woff[tok], 1);
      bidx[b * TT + p] = t;         // bucket order arbitrary; output order-invariant
    }
    return;
  }

  int b = bx;
  int d = tid & 255;
  int ks = tid >> 8;       // 0..3 (consumer / in_proj layout)
  int k0 = ks * 64;
  int kseg = tid >> 6;     // 0..15 (mv8x2 layout)
  int cq = tid & 63;

  // ---- context = (histogram @ embed) / T, branch-free ----
  for (int i = tid; i < VOCAB; i += 1024) cnt[i] = 0;
  __syncthreads();
  for (int t = tid; t < TT; t += 1024) atomicAdd(&cnt[tokens[b * TT + t]], 1);
  __syncthreads();
  {
    const float* Ep = embed + (size_t)kseg * 16 * DIM + cq * 4;
    float4 acc = {0.f, 0.f, 0.f, 0.f};
#pragma unroll 1
    for (int h = 0; h < 2; ++h) {
      float4 ev[8];
#pragma unroll
      for (int i = 0; i < 8; ++i)
        ev[i] = *(const float4*)(Ep + (size_t)(h * 8 + i) * DIM);
#pragma unroll
      for (int i = 0; i < 8; ++i) {
        float cv = (float)cnt[kseg * 16 + h * 8 + i];
        acc.x = fmaf(cv, ev[i].x, acc.x);
        acc.y = fmaf(cv, ev[i].y, acc.y);
        acc.z = fmaf(cv, ev[i].z, acc.z);
        acc.w = fmaf(cv, ev[i].w, acc.w);
      }
      __builtin_amdgcn_sched_barrier(0);
    }
    *(float4*)&red16[kseg][cq * 4] = acc;
  }
  __syncthreads();
  if (ks == 0) {
    float s = sum16(red16, d);
    s = fmaf((float)cnt[256], embed[(size_t)256 * DIM + d], s);
    sv[d] = s * (1.0f / (float)TT);
  }
  __syncthreads();

  mv8x2(sv, pin_w, kseg, cq, red16);
  __syncthreads();
  if (ks == 0) {
    float base = sum16(red16, d) + pin_b[d];
    basev[d] = base;
    float u = (base + depth_bias[4 * DIM + d] + pch_b[d]) * sigm(level_gate[4]);
    sv[d] = fmaxf(u, 0.f);
  }
  __syncthreads();
  mv8x2(sv, o_w, kseg, cq, red16);
  __syncthreads();
  if (ks == 0) {
    float y = sum16(red16, d) + o_b[d];
    ym[4][d] = y;
    sv[d] = y;
  }
  __syncthreads();
  for (int l = 3; l >= 0; --l) {
    mv8x2(sv, v_w, kseg, cq, red16);
    __syncthreads();
    if (ks == 0) {
      float vv = sum16(red16, d) + v_b[d];
      sv[d] = sigm(depth_gate[l * DIM + d]) * vv;   // uniform softmax -> child = v
    }
    __syncthreads();
    mv8x2(sv, pch_w, kseg, cq, red16);
    __syncthreads();
    if (ks == 0) {
      float t = sum16(red16, d) + pch_b[d];
      float u = (basev[d] + depth_bias[l * DIM + d] + t) * sigm(level_gate[l]);
      sv[d] = fmaxf(u, 0.f);
    }
    __syncthreads();
    mv8x2(sv, o_w, kseg, cq, red16);
    __syncthreads();
    if (ks == 0) {
      float y = sum16(red16, d) + o_b[d];
      ym[l][d] = y;
      sv[d] = y;
    }
    __syncthreads();
  }
  // ---- in_proj, ALL levels in ONE pass over the weights (8-deep batches) ----
  {
    float aq = 0.f;
    float ak0 = 0.f, ak1 = 0.f, ak2 = 0.f, ak3 = 0.f, ak4 = 0.f;
    float av0 = 0.f, av1 = 0.f, av2 = 0.f, av3 = 0.f, av4 = 0.f;
#pragma unroll
    for (int h = 0; h < 8; ++h) {
      int kb = k0 + h * 8;
      float wq[8], wk[8], wv8[8];
#pragma unroll
      for (int i = 0; i < 8; ++i) {
        const float* wrow = in_proj_w + (size_t)(kb + i) * 768;
        wq[i] = wrow[d]; wk[i] = wrow[256 + d]; wv8[i] = wrow[512 + d];
      }
#pragma unroll
      for (int i = 0; i < 8; ++i) {
        float z0 = ym[0][kb + i];
        aq  = fmaf(z0, wq[i], aq);
        ak0 = fmaf(z0, wk[i], ak0);
        av0 = fmaf(z0, wv8[i], av0);
        float z1 = ym[1][kb + i];
        ak1 = fmaf(z1, wk[i], ak1);
        av1 = fmaf(z1, wv8[i], av1);
        float z2 = ym[2][kb + i];
        ak2 = fmaf(z2, wk[i], ak2);
        av2 = fmaf(z2, wv8[i], av2);
        float z3 = ym[3][kb + i];
        ak3 = fmaf(z3, wk[i], ak3);
        av3 = fmaf(z3, wv8[i], av3);
        float z4 = ym[4][kb + i];
        ak4 = fmaf(z4, wk[i], ak4);
        av4 = fmaf(z4, wv8[i], av4);
      }
    }
    red11[ks][0][d] = ak0; red11[ks][1][d] = ak1; red11[ks][2][d] = ak2;
    red11[ks][3][d] = ak3; red11[ks][4][d] = ak4;
    red11[ks][5][d] = av0; red11[ks][6][d] = av1; red11[ks][7][d] = av2;
    red11[ks][8][d] = av3; red11[ks][9][d] = av4;
    red11[ks][10][d] = aq;
  }
  __syncthreads();
  for (int idx = tid; idx < 11 * DIM; idx += 1024) {
    int c = idx >> 8, dd = idx & 255;
    float sum = red11[0][c][dd] + red11[1][c][dd] + red11[2][c][dd] + red11[3][c][dd];
    if (c < 5)       kh[c][dd]     = sum + in_proj_b[256 + dd];
    else if (c < 10) vh[c - 5][dd] = sum + in_proj_b[512 + dd];
    else             q0v[dd]       = sum + in_proj_b[dd];
  }
  __syncthreads();
  {
    int wid = tid >> 6;
    if (wid < 10) {
      int h = wid / 5, l = wid - h * 5;
      int lane = tid & 63;
      float s = q0v[h * 128 + lane] * kh[l][h * 128 + lane];
      s = fmaf(q0v[h * 128 + 64 + lane], kh[l][h * 128 + 64 + lane], s);
      for (int o = 32; o > 0; o >>= 1) s += __shfl_down(s, o, 64);
      if (lane == 0) aw[wid] = s * 0.08838834764831845f;  // 1/sqrt(128)
    }
  }
  __syncthreads();
  if (tid < 2) {
    float m = aw[tid * 5];
    for (int l = 1; l < 5; ++l) m = fmaxf(m, aw[tid * 5 + l]);
    float e[5], ssum = 0.f;
    for (int l = 0; l < 5; ++l) { e[l] = expf(aw[tid * 5 + l] - m); ssum += e[l]; }
    for (int l = 0; l < 5; ++l) aw[tid * 5 + l] = e[l] / ssum;
  }
  __syncthreads();
  if (ks == 0) {
    int h = d >> 7;
    float z2 = 0.f;
    for (int l = 0; l < 5; ++l) z2 = fmaf(aw[h * 5 + l], vh[l][d], z2);
    sv[d] = z2;
  }
  __syncthreads();
  mv8x2(sv, out_proj_w, kseg, cq, red16);
  __syncthreads();
  if (ks == 0) {
    float z2p = sum16(red16, d) + out_proj_b[d];
    zsv[d] = ym[0][d] + z2p;
  }
  __syncthreads();
  float zs = 0.f, df = 0.f, mu = 0.f;
  if (tid < 256) {
    zs = zsv[tid];
    float v = zs;
    for (int o = 32; o > 0; o >>= 1) v += __shfl_down(v, o, 64);
    if ((tid & 63) == 0) redl[tid >> 6] = v;
  }
  __syncthreads();
  if (tid < 256) {
    mu = (redl[0] + redl[1] + redl[2] + redl[3]) * (1.f / 256.f);
    df = zs - mu;
  }
  __syncthreads();
  if (tid < 256) {
    float v = df * df;
    for (int o = 32; o > 0; o >>= 1) v += __shfl_down(v, o, 64);
    if ((tid & 63) == 0) redl[tid >> 6] = v;
  }
  __syncthreads();
  if (tid < 256) {
    float var = (redl[0] + redl[1] + redl[2] + redl[3]) * (1.f / 256.f);
    float zn = df / sqrtf(var + 1e-5f) * ln_g[tid] + ln_b[tid];
    float r = ym[0][tid] + sigm(ic_gate[0]) * zn;
    rootA[b * DIM + tid] = r;
    root2[b * DIM + tid] = r;   // experts atomically add on top
  }
}

// ---- fused MoE: gating + GEMM1 + partial-GEMM2 + combine -------------------
// Blocks 0..63 = 8 experts x 8 tiles of 64 HID cols (unchanged from R7).
// Blocks 64..255 = warm-up streamers for ew1/ew2 (8.4MB, cold every iteration).
__global__ void __launch_bounds__(256) k_moe(
    const float* __restrict__ rootA,
    const float* __restrict__ gate_w, const float* __restrict__ gate_b,
    const float* __restrict__ ew1, const float* __restrict__ eb1,
    const float* __restrict__ ew2, const float* __restrict__ eb2,
    float* __restrict__ root2) {
  int bx = blockIdx.x;
  int tid = threadIdx.x;
  if (bx >= 64) {
    // warm-up: one 64KB region of ew1/ew2 (128 regions, covered 1.5x)
    int r = (bx - 64) % 128;
    const float* W = (r < 64) ? ew1 + (size_t)r * 16384
                              : ew2 + (size_t)(r - 64) * 16384;
    const float4* src = (const float4*)W + tid;
    float sx = 0.f, sy = 0.f, sz = 0.f, sw = 0.f;
#pragma unroll 4
    for (int i = 0; i < 16; ++i) {
      float4 v = src[i * 256];
      sx += v.x; sy += v.y; sz += v.z; sw += v.w;
    }
    asm volatile("" :: "v"(sx), "v"(sy), "v"(sz), "v"(sw));
    return;
  }
  int e = bx >> 3, jt = bx & 7, j0 = jt * 64;
  int w = tid >> 6, lane = tid & 63;
  __shared__ float rlds[BB * DIM];      // 16KB rootA copy
  __shared__ float gwlds[DIM * NEXP];   // 8KB gate_w copy
  __shared__ float xin[CAP][DIM];
  __shared__ float red[CAP][4][64];
  __shared__ float hloc[CAP][64];
  __shared__ float sc[BB * NEXP];
  __shared__ float gs[BB * TOPK];
  __shared__ int gidx[BB * TOPK];
  __shared__ int stok[CAP];
  __shared__ float swt[CAP];
  for (int idx = tid; idx < BB * DIM / 4; idx += 256)
    *(float4*)&rlds[idx * 4] = *(const float4*)&rootA[idx * 4];
  for (int idx = tid; idx < DIM * NEXP / 4; idx += 256)
    *(float4*)&gwlds[idx * 4] = *(const float4*)&gate_w[idx * 4];
  __syncthreads();
  if (tid < BB * NEXP) {
    int b = tid >> 3, ep = tid & 7;
    float chunk[8];
#pragma unroll
    for (int g = 0; g < 8; ++g) {
      float acc = 0.f;
#pragma unroll 8
      for (int i = 0; i < 32; ++i) {
        int k = g * 32 + i;
        acc = fmaf(rlds[b * DIM + k], gwlds[k * NEXP + ep], acc);
      }
      chunk[g] = acc;
    }
    float s = gate_b[ep];
#pragma unroll
    for (int g = 0; g < 8; ++g) s += chunk[g];
    sc[tid] = s;
  }
  __syncthreads();
  if (tid < BB) {  // top-2 + softmax per batch (identical order to old k_gate)
    int bb = tid;
    int i0 = 0; float v0 = sc[bb * 8 + 0];
    for (int ee = 1; ee < 8; ++ee) { float v = sc[bb * 8 + ee]; if (v > v0) { v0 = v; i0 = ee; } }
    int i1 = -1; float v1 = -1e30f;
    for (int ee = 0; ee < 8; ++ee) {
      if (ee == i0) continue;
      float v = sc[bb * 8 + ee];
      if (v > v1) { v1 = v; i1 = ee; }
    }
    float e1v = expf(v1 - v0);
    float s = 1.f + e1v;
    gs[bb * 2 + 0] = 1.f / s;  gidx[bb * 2 + 0] = i0;
    gs[bb * 2 + 1] = e1v / s;  gidx[bb * 2 + 1] = i1;
  }
  __syncthreads();
  if (tid == 0) {  // top-CAP for own expert: bitmask, value desc / index asc
    unsigned used = 0u;
    for (int s = 0; s < CAP; ++s) {
      int bi = 0; float bv = -1e30f;
      for (int i = 0; i < 32; ++i) {
        if (used & (1u << i)) continue;
        float v = (gidx[i] == e) ? gs[i] : -1.0f;
        if (v > bv) { bv = v; bi = i; }
      }
      used |= (1u << bi);
      stok[s] = bi >> 1;
      swt[s] = bv > 0.f ? bv : 0.f;
    }
  }
  __syncthreads();
  for (int idx = tid; idx < CAP * DIM; idx += 256) {
    int s = idx >> 8, k = idx & 255;
    xin[s][k] = rlds[stok[s] * DIM + k];
  }
  __syncthreads();
  // GEMM1: this block's 64 HID cols (identical order to old k_expert1)
  {
    float a0 = 0.f, a1 = 0.f, a2 = 0.f, a3 = 0.f, a4 = 0.f;
    const float* W = ew1 + (size_t)e * DIM * HID + j0 + lane;  // row k -> +k*HID
    int kbase = w * 64;
#pragma unroll
    for (int h = 0; h < 8; ++h) {
      float wv[8];
#pragma unroll
      for (int i = 0; i < 8; ++i) wv[i] = W[(size_t)(kbase + h * 8 + i) * HID];
#pragma unroll
      for (int i = 0; i < 8; ++i) {
        int k = kbase + h * 8 + i;
        a0 = fmaf(xin[0][k], wv[i], a0);
        a1 = fmaf(xin[1][k], wv[i], a1);
        a2 = fmaf(xin[2][k], wv[i], a2);
        a3 = fmaf(xin[3][k], wv[i], a3);
        a4 = fmaf(xin[4][k], wv[i], a4);
      }
    }
    red[0][w][lane] = a0; red[1][w][lane] = a1; red[2][w][lane] = a2;
    red[3][w][lane] = a3; red[4][w][lane] = a4;
  }
  __syncthreads();
  for (int idx = tid; idx < CAP * 64; idx += 256) {
    int s = idx >> 6, j = idx & 63;
    float sum = red[s][0][j] + red[s][1][j] + red[s][2][j] + red[s][3][j]
              + eb1[e * HID + j0 + j];
    hloc[s][j] = fmaxf(sum, 0.f);
  }
  __syncthreads();
  // partial GEMM2: K = this block's 64 hid cols, d = tid (0..255)
  {
    int d = tid;
    float a0 = 0.f, a1 = 0.f, a2 = 0.f, a3 = 0.f, a4 = 0.f;
    const float* W2 = ew2 + (size_t)e * HID * DIM + (size_t)j0 * DIM + d;
#pragma unroll
    for (int h = 0; h < 8; ++h) {
      float wv[8];
#pragma unroll
      for (int i = 0; i < 8; ++i) wv[i] = W2[(size_t)(h * 8 + i) * DIM];
#pragma unroll
      for (int i = 0; i < 8; ++i) {
        int j = h * 8 + i;
        a0 = fmaf(hloc[0][j], wv[i], a0);
        a1 = fmaf(hloc[1][j], wv[i], a1);
        a2 = fmaf(hloc[2][j], wv[i], a2);
        a3 = fmaf(hloc[3][j], wv[i], a3);
        a4 = fmaf(hloc[4][j], wv[i], a4);
      }
    }
    float bias = (jt == 0) ? eb2[e * DIM + d] : 0.f;
#pragma unroll
    for (int s = 0; s < CAP; ++s) {
      float as = (s == 0) ? a0 : (s == 1) ? a1 : (s == 2) ? a2 : (s == 3) ? a3 : a4;
      float wgt = swt[s];
      if (wgt > 0.f)
        atomicAdd(&root2[stok[s] * DIM + d], (as + bias) * wgt);
    }
  }
}

// ---- logits + fused scatter: grid (257 tokens x 4 rowgroups) x 256 threads --
// R5-proven shape: 1028 blocks keeps the machine latency-tolerant; weights
// (520KB) are L2-resident so redundant reads are cheap. (R6's 16-row/257-block
// variant: 1 block/CU, serial chain 4x longer -> 205us. Reverted.)
__global__ void __launch_bounds__(256) k_logits(
    const float* __restrict__ embed, const float* __restrict__ root2,
    const float* __restrict__ hw1, const float* __restrict__ hb1,
    const float* __restrict__ hw2, const float* __restrict__ hb2,
    const int* __restrict__ bidx, const int* __restrict__ boff,
    float* __restrict__ out) {
  int tok = blockIdx.x, r0 = blockIdx.y * 4;
  int c = threadIdx.x;
  __shared__ float hrow[4][DIM];
  __shared__ float hid[4][DIM];
  __shared__ float tailred[4][17];
  __shared__ float tailv[4];
  {
    float ev = embed[(size_t)tok * DIM + c];
#pragma unroll
    for (int j = 0; j < 4; ++j) hrow[j][c] = ev + root2[(size_t)(r0 + j) * DIM + c];
  }
  __syncthreads();
  // GEMM1: col c over K=256, 4 rows
  {
    float a0 = hb1[c], a1 = a0, a2 = a0, a3 = a0;
    for (int kb = 0; kb < DIM; kb += 8) {
      float wv[8];
#pragma unroll
      for (int i = 0; i < 8; ++i) wv[i] = hw1[(size_t)(kb + i) * DIM + c];
#pragma unroll
      for (int i = 0; i < 8; ++i) {
        int k = kb + i;
        a0 = fmaf(hrow[0][k], wv[i], a0);
        a1 = fmaf(hrow[1][k], wv[i], a1);
        a2 = fmaf(hrow[2][k], wv[i], a2);
        a3 = fmaf(hrow[3][k], wv[i], a3);
      }
    }
    hid[0][c] = fmaxf(a0, 0.f); hid[1][c] = fmaxf(a1, 0.f);
    hid[2][c] = fmaxf(a2, 0.f); hid[3][c] = fmaxf(a3, 0.f);
  }
  __syncthreads();
  // GEMM2: cols 0..255 into registers
  float a0, a1, a2, a3;
  {
    a0 = hb2[c]; a1 = a0; a2 = a0; a3 = a0;
    for (int kb = 0; kb < DIM; kb += 8) {
      float wv[8];
#pragma unroll
      for (int i = 0; i < 8; ++i) wv[i] = hw2[(size_t)(kb + i) * VOCAB + c];
#pragma unroll
      for (int i = 0; i < 8; ++i) {
        int k = kb + i;
        a0 = fmaf(hid[0][k], wv[i], a0);
        a1 = fmaf(hid[1][k], wv[i], a1);
        a2 = fmaf(hid[2][k], wv[i], a2);
        a3 = fmaf(hid[3][k], wv[i], a3);
      }
    }
  }
  // tail column 256: 16-way K-split across first 64 threads
  if (c < 64) {
    int r = c >> 4, seg = c & 15;
    float sum = 0.f;
#pragma unroll 4
    for (int i = 0; i < 16; ++i) {
      int k = seg * 16 + i;
      sum = fmaf(hid[r][k], hw2[(size_t)k * VOCAB + 256], sum);
    }
    tailred[r][seg] = sum;
  }
  __syncthreads();
  if (c < 4) {
    float a = hb2[256];
#pragma unroll
    for (int s = 0; s < 16; ++s) a += tailred[c][s];
    tailv[c] = a;
  }
  __syncthreads();
  // fused scatter: write this row to every matching t (coalesced 1KB rows)
#pragma unroll
  for (int j = 0; j < 4; ++j) {
    int b = r0 + j;
    int s = boff[b * (VOCAB + 1) + tok];
    int e = boff[b * (VOCAB + 1) + tok + 1];
    float aj = (j == 0) ? a0 : (j == 1) ? a1 : (j == 2) ? a2 : a3;
    float tl = tailv[j];
    for (int m = s; m < e; ++m) {
      int t = bidx[b * TT + m];
      size_t base = (size_t)(b * TT + t) * VOCAB;
      out[base + c] = aj;
      if (c == 0) out[base + 256] = tl;
    }
  }
}

extern "C" void kernel_launch(void* const* d_in, const int* in_sizes, int n_in,
                              void* d_out, int out_size, void* d_ws, size_t ws_size,
                              hipStream_t stream) {
  (void)in_sizes; (void)n_in; (void)out_size; (void)ws_size;
  const int*   tokens     = (const int*)d_in[0];
  const float* embed      = (const float*)d_in[1];
  const float* pin_w      = (const float*)d_in[2];
  const float* pin_b      = (const float*)d_in[3];
  const float* pch_w      = (const float*)d_in[4];
  const float* pch_b      = (const float*)d_in[5];
  const float* depth_bias = (const float*)d_in[6];
  // d_in[7..10] = q_w,q_b,k_w,k_b: provably unused (uniform softmax)
  const float* v_w        = (const float*)d_in[11];
  const float* v_b        = (const float*)d_in[12];
  const float* o_w        = (const float*)d_in[13];
  const float* o_b        = (const float*)d_in[14];
  const float* level_gate = (const float*)d_in[15];
  const float* depth_gate = (const float*)d_in[16];
  const float* in_proj_w  = (const float*)d_in[17];
  const float* in_proj_b  = (const float*)d_in[18];
  const float* out_proj_w = (const float*)d_in[19];
  const float* out_proj_b = (const float*)d_in[20];
  const float* ln_g       = (const float*)d_in[21];
  const float* ln_b       = (const float*)d_in[22];
  const float* ic_gate    = (const float*)d_in[23];
  const float* gate_w     = (const float*)d_in[24];
  const float* gate_b     = (const float*)d_in[25];
  const float* ew1        = (const float*)d_in[26];
  const float* eb1        = (const float*)d_in[27];
  const float* ew2        = (const float*)d_in[28];
  const float* eb2        = (const float*)d_in[29];
  const float* hw1        = (const float*)d_in[30];
  const float* hb1        = (const float*)d_in[31];
  const float* hw2        = (const float*)d_in[32];
  const float* hb2        = (const float*)d_in[33];
  float* out = (float*)d_out;

  float* ws      = (float*)d_ws;
  float* rootA   = ws + 4096;            // 4096 floats
  float* root2   = ws + 8192;            // 4096 floats
  int*   bidx    = (int*)(ws + 43136);   // 16*2048 = 32768 ints
  int*   boff    = (int*)(ws + 75904);   // 16*258  =  4128 ints

  k_fractal<<<256, 1024, 0, stream>>>(tokens, embed, pin_w, pin_b, pch_w, pch_b,
                                      depth_bias, v_w, v_b, o_w, o_b, level_gate,
                                      depth_gate, in_proj_w, in_proj_b, out_proj_w,
                                      out_proj_b, ln_g, ln_b, ic_gate, rootA, root2,
                                      bidx, boff);
  k_moe<<<256, 256, 0, stream>>>(rootA, gate_w, gate_b, ew1, eb1,
                                 ew2, eb2, root2);
  k_logits<<<dim3(VOCAB, 4), 256, 0, stream>>>(embed, root2, hw1, hb1, hw2, hb2,
                                               bidx, boff, out);
}

// Round 9
// 230.635 us; speedup vs baseline: 1.7204x; 1.0157x over previous
//
#include <hip/hip_runtime.h>
#include <hip/hip_bf16.h>
#include <math.h>

#define DIM    256
#define DEPTH  5
#define FANOUT 10
#define VOCAB  257
#define BB     16
#define TT     2048
#define NEXP   8
#define HID    512
#define TOPK   2
#define CAP    5   // ceil(16*2/8*1.1)

__device__ __forceinline__ float sigm(float x) { return 1.f / (1.f + expf(-x)); }

// 256x256 matvec partial: 1024 threads = 16 ksegs x 64 col-quads.
// Depth-8 float4 batches inside a KEPT loop (#pragma unroll 1): 2 latency
// exposures per matvec. R1-R3 lesson: fully-unrolled forms get ALL loads
// hoisted and spill 10MB/dispatch; only a real loop boundary stops the hoist.
__device__ __forceinline__ void mv8x2(const float* sv, const float* __restrict__ W,
                                      int kseg, int cq, float red[16][DIM]) {
  const float* Wp = W + (size_t)kseg * 16 * DIM + cq * 4;
  float4 acc = {0.f, 0.f, 0.f, 0.f};
#pragma unroll 1
  for (int h = 0; h < 2; ++h) {
    float4 wv[8];
#pragma unroll
    for (int i = 0; i < 8; ++i)
      wv[i] = *(const float4*)(Wp + (size_t)(h * 8 + i) * DIM);
#pragma unroll
    for (int i = 0; i < 8; ++i) {
      float s = sv[kseg * 16 + h * 8 + i];
      acc.x = fmaf(s, wv[i].x, acc.x);
      acc.y = fmaf(s, wv[i].y, acc.y);
      acc.z = fmaf(s, wv[i].z, acc.z);
      acc.w = fmaf(s, wv[i].w, acc.w);
    }
    __builtin_amdgcn_sched_barrier(0);
  }
  *(float4*)&red[kseg][cq * 4] = acc;
}

__device__ __forceinline__ float sum16(const float red[16][DIM], int d) {
  float s = 0.f;
#pragma unroll
  for (int g = 0; g < 16; ++g) s += red[g][d];
  return s;
}

// ------ collapsed fractal + context + root2 init ------------------------------
// Grid = 256 blocks, role = bx&7 (XCD id, round-robin block->XCD mapping):
//   xcd 0, slot 0..15  : the 16 real per-batch chains  -> ALL ON ONE XCD, so
//                        only ONE private L2 must hold the 2.4MB weight set
//                        (R8: chains spread 2/XCD forced 8x duplicate fills,
//                        FETCH 9.5MB ~= 4x the unique set).
//   xcd 0, slot 16..31 : warmers streaming the 37x64KB weight regions into
//                        XCD0's L2 while real blocks do the histogram phase.
//   xcd 1, slot 0..15  : token-CSR build (independent of the chain).
//   everything else    : exit.
__global__ void __launch_bounds__(1024) k_fractal(
    const int* __restrict__ tokens, const float* __restrict__ embed,
    const float* __restrict__ pin_w, const float* __restrict__ pin_b,
    const float* __restrict__ pch_w, const float* __restrict__ pch_b,
    const float* __restrict__ depth_bias,
    const float* __restrict__ v_w, const float* __restrict__ v_b,
    const float* __restrict__ o_w, const float* __restrict__ o_b,
    const float* __restrict__ level_gate, const float* __restrict__ depth_gate,
    const float* __restrict__ in_proj_w, const float* __restrict__ in_proj_b,
    const float* __restrict__ out_proj_w, const float* __restrict__ out_proj_b,
    const float* __restrict__ ln_g, const float* __restrict__ ln_b,
    const float* __restrict__ ic_gate,
    float* __restrict__ rootA, float* __restrict__ root2,
    int* __restrict__ bidx, int* __restrict__ boff) {
  int bx = blockIdx.x;
  int tid = threadIdx.x;
  int xcd = bx & 7, slot = bx >> 3;
  __shared__ int cnt[VOCAB];
  __shared__ float sv[DIM];
  __shared__ float basev[DIM];
  __shared__ float ym[DEPTH][DIM];
  __shared__ float q0v[DIM], kh[DEPTH][DIM], vh[DEPTH][DIM];
  __shared__ float red11[4][11][DIM];   // in_proj reduction; also aliases red16
  __shared__ float zsv[DIM];
  __shared__ float aw[16];
  __shared__ float redl[8];
  __shared__ int offb[VOCAB + 1];
  __shared__ int woff[VOCAB];
  float (*red16)[DIM] = reinterpret_cast<float(*)[DIM]>(&red11[0][0][0]); // 16KB of 44KB

  if (xcd == 1) {
    if (slot < BB) {
      // ---- token CSR for batch b: off the chain's critical path ----
      int b = slot;
      for (int i = tid; i < VOCAB; i += 1024) cnt[i] = 0;
      __syncthreads();
      for (int t = tid; t < TT; t += 1024) atomicAdd(&cnt[tokens[b * TT + t]], 1);
      __syncthreads();
      if (tid == 0) {
        int a = 0;
        for (int v = 0; v < VOCAB; ++v) { offb[v] = a; a += cnt[v]; }
        offb[VOCAB] = a;              // == TT
      }
      __syncthreads();
      if (tid <= VOCAB) boff[b * (VOCAB + 1) + tid] = offb[tid];
      if (tid < VOCAB) woff[tid] = offb[tid];
      __syncthreads();
      for (int t = tid; t < TT; t += 1024) {
        int tok = tokens[b * TT + t];
        int p = atomicAdd(&woff[tok], 1);
        bidx[b * TT + p] = t;         // bucket order arbitrary; output order-invariant
      }
    }
    return;
  }
  if (xcd != 0) return;
  if (slot >= BB) {
    // ---- warmer: 3 of the 37 64KB weight regions into XCD0's L2 ----
    int w = slot - BB;                // 0..15
    float sx = 0.f, sy = 0.f, sz = 0.f, sw = 0.f;
#pragma unroll 1
    for (int q = 0; q < 3; ++q) {
      int r = w * 3 + q;
      if (r >= 37) break;
      const float* W; int n = 16384;
      if (r < 4)       W = pin_w      + (size_t)r * 16384;
      else if (r < 8)  W = pch_w      + (size_t)(r - 4) * 16384;
      else if (r < 12) W = v_w        + (size_t)(r - 8) * 16384;
      else if (r < 16) W = o_w        + (size_t)(r - 12) * 16384;
      else if (r < 20) W = out_proj_w + (size_t)(r - 16) * 16384;
      else if (r < 32) W = in_proj_w  + (size_t)(r - 20) * 16384;
      else { W = embed + (size_t)(r - 32) * 16384; n = 65792 - (r - 32) * 16384;
             if (n > 16384) n = 16384; }
      const float4* src = (const float4*)W + tid;
#pragma unroll
      for (int k = 0; k < 4; ++k) {
        int p = tid * 4 + k * 4096;
        if (p + 4 <= n) {
          float4 v = src[k * 1024];
          sx += v.x; sy += v.y; sz += v.z; sw += v.w;
        }
      }
    }
    asm volatile("" :: "v"(sx), "v"(sy), "v"(sz), "v"(sw));
    return;
  }

  int b = slot;
  int d = tid & 255;
  int ks = tid >> 8;       // 0..3 (consumer / in_proj layout)
  int k0 = ks * 64;
  int kseg = tid >> 6;     // 0..15 (mv8x2 layout)
  int cq = tid & 63;

  // ---- context = (histogram @ embed) / T, branch-free ----
  for (int i = tid; i < VOCAB; i += 1024) cnt[i] = 0;
  __syncthreads();
  for (int t = tid; t < TT; t += 1024) atomicAdd(&cnt[tokens[b * TT + t]], 1);
  __syncthreads();
  {
    const float* Ep = embed + (size_t)kseg * 16 * DIM + cq * 4;
    float4 acc = {0.f, 0.f, 0.f, 0.f};
#pragma unroll 1
    for (int h = 0; h < 2; ++h) {
      float4 ev[8];
#pragma unroll
      for (int i = 0; i < 8; ++i)
        ev[i] = *(const float4*)(Ep + (size_t)(h * 8 + i) * DIM);
#pragma unroll
      for (int i = 0; i < 8; ++i) {
        float cv = (float)cnt[kseg * 16 + h * 8 + i];
        acc.x = fmaf(cv, ev[i].x, acc.x);
        acc.y = fmaf(cv, ev[i].y, acc.y);
        acc.z = fmaf(cv, ev[i].z, acc.z);
        acc.w = fmaf(cv, ev[i].w, acc.w);
      }
      __builtin_amdgcn_sched_barrier(0);
    }
    *(float4*)&red16[kseg][cq * 4] = acc;
  }
  __syncthreads();
  if (ks == 0) {
    float s = sum16(red16, d);
    s = fmaf((float)cnt[256], embed[(size_t)256 * DIM + d], s);
    sv[d] = s * (1.0f / (float)TT);
  }
  __syncthreads();

  mv8x2(sv, pin_w, kseg, cq, red16);
  __syncthreads();
  if (ks == 0) {
    float base = sum16(red16, d) + pin_b[d];
    basev[d] = base;
    float u = (base + depth_bias[4 * DIM + d] + pch_b[d]) * sigm(level_gate[4]);
    sv[d] = fmaxf(u, 0.f);
  }
  __syncthreads();
  mv8x2(sv, o_w, kseg, cq, red16);
  __syncthreads();
  if (ks == 0) {
    float y = sum16(red16, d) + o_b[d];
    ym[4][d] = y;
    sv[d] = y;
  }
  __syncthreads();
  for (int l = 3; l >= 0; --l) {
    mv8x2(sv, v_w, kseg, cq, red16);
    __syncthreads();
    if (ks == 0) {
      float vv = sum16(red16, d) + v_b[d];
      sv[d] = sigm(depth_gate[l * DIM + d]) * vv;   // uniform softmax -> child = v
    }
    __syncthreads();
    mv8x2(sv, pch_w, kseg, cq, red16);
    __syncthreads();
    if (ks == 0) {
      float t = sum16(red16, d) + pch_b[d];
      float u = (basev[d] + depth_bias[l * DIM + d] + t) * sigm(level_gate[l]);
      sv[d] = fmaxf(u, 0.f);
    }
    __syncthreads();
    mv8x2(sv, o_w, kseg, cq, red16);
    __syncthreads();
    if (ks == 0) {
      float y = sum16(red16, d) + o_b[d];
      ym[l][d] = y;
      sv[d] = y;
    }
    __syncthreads();
  }
  // ---- in_proj, ALL levels in ONE pass over the weights (8-deep batches) ----
  {
    float aq = 0.f;
    float ak0 = 0.f, ak1 = 0.f, ak2 = 0.f, ak3 = 0.f, ak4 = 0.f;
    float av0 = 0.f, av1 = 0.f, av2 = 0.f, av3 = 0.f, av4 = 0.f;
#pragma unroll
    for (int h = 0; h < 8; ++h) {
      int kb = k0 + h * 8;
      float wq[8], wk[8], wv8[8];
#pragma unroll
      for (int i = 0; i < 8; ++i) {
        const float* wrow = in_proj_w + (size_t)(kb + i) * 768;
        wq[i] = wrow[d]; wk[i] = wrow[256 + d]; wv8[i] = wrow[512 + d];
      }
#pragma unroll
      for (int i = 0; i < 8; ++i) {
        float z0 = ym[0][kb + i];
        aq  = fmaf(z0, wq[i], aq);
        ak0 = fmaf(z0, wk[i], ak0);
        av0 = fmaf(z0, wv8[i], av0);
        float z1 = ym[1][kb + i];
        ak1 = fmaf(z1, wk[i], ak1);
        av1 = fmaf(z1, wv8[i], av1);
        float z2 = ym[2][kb + i];
        ak2 = fmaf(z2, wk[i], ak2);
        av2 = fmaf(z2, wv8[i], av2);
        float z3 = ym[3][kb + i];
        ak3 = fmaf(z3, wk[i], ak3);
        av3 = fmaf(z3, wv8[i], av3);
        float z4 = ym[4][kb + i];
        ak4 = fmaf(z4, wk[i], ak4);
        av4 = fmaf(z4, wv8[i], av4);
      }
    }
    red11[ks][0][d] = ak0; red11[ks][1][d] = ak1; red11[ks][2][d] = ak2;
    red11[ks][3][d] = ak3; red11[ks][4][d] = ak4;
    red11[ks][5][d] = av0; red11[ks][6][d] = av1; red11[ks][7][d] = av2;
    red11[ks][8][d] = av3; red11[ks][9][d] = av4;
    red11[ks][10][d] = aq;
  }
  __syncthreads();
  for (int idx = tid; idx < 11 * DIM; idx += 1024) {
    int c = idx >> 8, dd = idx & 255;
    float sum = red11[0][c][dd] + red11[1][c][dd] + red11[2][c][dd] + red11[3][c][dd];
    if (c < 5)       kh[c][dd]     = sum + in_proj_b[256 + dd];
    else if (c < 10) vh[c - 5][dd] = sum + in_proj_b[512 + dd];
    else             q0v[dd]       = sum + in_proj_b[dd];
  }
  __syncthreads();
  {
    int wid = tid >> 6;
    if (wid < 10) {
      int h = wid / 5, l = wid - h * 5;
      int lane = tid & 63;
      float s = q0v[h * 128 + lane] * kh[l][h * 128 + lane];
      s = fmaf(q0v[h * 128 + 64 + lane], kh[l][h * 128 + 64 + lane], s);
      for (int o = 32; o > 0; o >>= 1) s += __shfl_down(s, o, 64);
      if (lane == 0) aw[wid] = s * 0.08838834764831845f;  // 1/sqrt(128)
    }
  }
  __syncthreads();
  if (tid < 2) {
    float m = aw[tid * 5];
    for (int l = 1; l < 5; ++l) m = fmaxf(m, aw[tid * 5 + l]);
    float e[5], ssum = 0.f;
    for (int l = 0; l < 5; ++l) { e[l] = expf(aw[tid * 5 + l] - m); ssum += e[l]; }
    for (int l = 0; l < 5; ++l) aw[tid * 5 + l] = e[l] / ssum;
  }
  __syncthreads();
  if (ks == 0) {
    int h = d >> 7;
    float z2 = 0.f;
    for (int l = 0; l < 5; ++l) z2 = fmaf(aw[h * 5 + l], vh[l][d], z2);
    sv[d] = z2;
  }
  __syncthreads();
  mv8x2(sv, out_proj_w, kseg, cq, red16);
  __syncthreads();
  if (ks == 0) {
    float z2p = sum16(red16, d) + out_proj_b[d];
    zsv[d] = ym[0][d] + z2p;
  }
  __syncthreads();
  float zs = 0.f, df = 0.f, mu = 0.f;
  if (tid < 256) {
    zs = zsv[tid];
    float v = zs;
    for (int o = 32; o > 0; o >>= 1) v += __shfl_down(v, o, 64);
    if ((tid & 63) == 0) redl[tid >> 6] = v;
  }
  __syncthreads();
  if (tid < 256) {
    mu = (redl[0] + redl[1] + redl[2] + redl[3]) * (1.f / 256.f);
    df = zs - mu;
  }
  __syncthreads();
  if (tid < 256) {
    float v = df * df;
    for (int o = 32; o > 0; o >>= 1) v += __shfl_down(v, o, 64);
    if ((tid & 63) == 0) redl[tid >> 6] = v;
  }
  __syncthreads();
  if (tid < 256) {
    float var = (redl[0] + redl[1] + redl[2] + redl[3]) * (1.f / 256.f);
    float zn = df / sqrtf(var + 1e-5f) * ln_g[tid] + ln_b[tid];
    float r = ym[0][tid] + sigm(ic_gate[0]) * zn;
    rootA[b * DIM + tid] = r;
    root2[b * DIM + tid] = r;   // experts atomically add on top
  }
}

// ---- fused MoE: gating + GEMM1 + partial-GEMM2 + combine -------------------
// Blocks 0..63 = 8 experts x 8 tiles of 64 HID cols (unchanged from R7).
// Blocks 64..255 = warm-up streamers for ew1/ew2 (8.4MB, cold every iteration).
__global__ void __launch_bounds__(256) k_moe(
    const float* __restrict__ rootA,
    const float* __restrict__ gate_w, const float* __restrict__ gate_b,
    const float* __restrict__ ew1, const float* __restrict__ eb1,
    const float* __restrict__ ew2, const float* __restrict__ eb2,
    float* __restrict__ root2) {
  int bx = blockIdx.x;
  int tid = threadIdx.x;
  if (bx >= 64) {
    // warm-up: one 64KB region of ew1/ew2 (128 regions, covered 1.5x)
    int r = (bx - 64) % 128;
    const float* W = (r < 64) ? ew1 + (size_t)r * 16384
                              : ew2 + (size_t)(r - 64) * 16384;
    const float4* src = (const float4*)W + tid;
    float sx = 0.f, sy = 0.f, sz = 0.f, sw = 0.f;
#pragma unroll 4
    for (int i = 0; i < 16; ++i) {
      float4 v = src[i * 256];
      sx += v.x; sy += v.y; sz += v.z; sw += v.w;
    }
    asm volatile("" :: "v"(sx), "v"(sy), "v"(sz), "v"(sw));
    return;
  }
  int e = bx >> 3, jt = bx & 7, j0 = jt * 64;
  int w = tid >> 6, lane = tid & 63;
  __shared__ float rlds[BB * DIM];      // 16KB rootA copy
  __shared__ float gwlds[DIM * NEXP];   // 8KB gate_w copy
  __shared__ float xin[CAP][DIM];
  __shared__ float red[CAP][4][64];
  __shared__ float hloc[CAP][64];
  __shared__ float sc[BB * NEXP];
  __shared__ float gs[BB * TOPK];
  __shared__ int gidx[BB * TOPK];
  __shared__ int stok[CAP];
  __shared__ float swt[CAP];
  for (int idx = tid; idx < BB * DIM / 4; idx += 256)
    *(float4*)&rlds[idx * 4] = *(const float4*)&rootA[idx * 4];
  for (int idx = tid; idx < DIM * NEXP / 4; idx += 256)
    *(float4*)&gwlds[idx * 4] = *(const float4*)&gate_w[idx * 4];
  __syncthreads();
  if (tid < BB * NEXP) {
    int b = tid >> 3, ep = tid & 7;
    float chunk[8];
#pragma unroll
    for (int g = 0; g < 8; ++g) {
      float acc = 0.f;
#pragma unroll 8
      for (int i = 0; i < 32; ++i) {
        int k = g * 32 + i;
        acc = fmaf(rlds[b * DIM + k], gwlds[k * NEXP + ep], acc);
      }
      chunk[g] = acc;
    }
    float s = gate_b[ep];
#pragma unroll
    for (int g = 0; g < 8; ++g) s += chunk[g];
    sc[tid] = s;
  }
  __syncthreads();
  if (tid < BB) {  // top-2 + softmax per batch (identical order to old k_gate)
    int bb = tid;
    int i0 = 0; float v0 = sc[bb * 8 + 0];
    for (int ee = 1; ee < 8; ++ee) { float v = sc[bb * 8 + ee]; if (v > v0) { v0 = v; i0 = ee; } }
    int i1 = -1; float v1 = -1e30f;
    for (int ee = 0; ee < 8; ++ee) {
      if (ee == i0) continue;
      float v = sc[bb * 8 + ee];
      if (v > v1) { v1 = v; i1 = ee; }
    }
    float e1v = expf(v1 - v0);
    float s = 1.f + e1v;
    gs[bb * 2 + 0] = 1.f / s;  gidx[bb * 2 + 0] = i0;
    gs[bb * 2 + 1] = e1v / s;  gidx[bb * 2 + 1] = i1;
  }
  __syncthreads();
  if (tid == 0) {  // top-CAP for own expert: bitmask, value desc / index asc
    unsigned used = 0u;
    for (int s = 0; s < CAP; ++s) {
      int bi = 0; float bv = -1e30f;
      for (int i = 0; i < 32; ++i) {
        if (used & (1u << i)) continue;
        float v = (gidx[i] == e) ? gs[i] : -1.0f;
        if (v > bv) { bv = v; bi = i; }
      }
      used |= (1u << bi);
      stok[s] = bi >> 1;
      swt[s] = bv > 0.f ? bv : 0.f;
    }
  }
  __syncthreads();
  for (int idx = tid; idx < CAP * DIM; idx += 256) {
    int s = idx >> 8, k = idx & 255;
    xin[s][k] = rlds[stok[s] * DIM + k];
  }
  __syncthreads();
  // GEMM1: this block's 64 HID cols (identical order to old k_expert1)
  {
    float a0 = 0.f, a1 = 0.f, a2 = 0.f, a3 = 0.f, a4 = 0.f;
    const float* W = ew1 + (size_t)e * DIM * HID + j0 + lane;  // row k -> +k*HID
    int kbase = w * 64;
#pragma unroll
    for (int h = 0; h < 8; ++h) {
      float wv[8];
#pragma unroll
      for (int i = 0; i < 8; ++i) wv[i] = W[(size_t)(kbase + h * 8 + i) * HID];
#pragma unroll
      for (int i = 0; i < 8; ++i) {
        int k = kbase + h * 8 + i;
        a0 = fmaf(xin[0][k], wv[i], a0);
        a1 = fmaf(xin[1][k], wv[i], a1);
        a2 = fmaf(xin[2][k], wv[i], a2);
        a3 = fmaf(xin[3][k], wv[i], a3);
        a4 = fmaf(xin[4][k], wv[i], a4);
      }
    }
    red[0][w][lane] = a0; red[1][w][lane] = a1; red[2][w][lane] = a2;
    red[3][w][lane] = a3; red[4][w][lane] = a4;
  }
  __syncthreads();
  for (int idx = tid; idx < CAP * 64; idx += 256) {
    int s = idx >> 6, j = idx & 63;
    float sum = red[s][0][j] + red[s][1][j] + red[s][2][j] + red[s][3][j]
              + eb1[e * HID + j0 + j];
    hloc[s][j] = fmaxf(sum, 0.f);
  }
  __syncthreads();
  // partial GEMM2: K = this block's 64 hid cols, d = tid (0..255)
  {
    int d = tid;
    float a0 = 0.f, a1 = 0.f, a2 = 0.f, a3 = 0.f, a4 = 0.f;
    const float* W2 = ew2 + (size_t)e * HID * DIM + (size_t)j0 * DIM + d;
#pragma unroll
    for (int h = 0; h < 8; ++h) {
      float wv[8];
#pragma unroll
      for (int i = 0; i < 8; ++i) wv[i] = W2[(size_t)(h * 8 + i) * DIM];
#pragma unroll
      for (int i = 0; i < 8; ++i) {
        int j = h * 8 + i;
        a0 = fmaf(hloc[0][j], wv[i], a0);
        a1 = fmaf(hloc[1][j], wv[i], a1);
        a2 = fmaf(hloc[2][j], wv[i], a2);
        a3 = fmaf(hloc[3][j], wv[i], a3);
        a4 = fmaf(hloc[4][j], wv[i], a4);
      }
    }
    float bias = (jt == 0) ? eb2[e * DIM + d] : 0.f;
#pragma unroll
    for (int s = 0; s < CAP; ++s) {
      float as = (s == 0) ? a0 : (s == 1) ? a1 : (s == 2) ? a2 : (s == 3) ? a3 : a4;
      float wgt = swt[s];
      if (wgt > 0.f)
        atomicAdd(&root2[stok[s] * DIM + d], (as + bias) * wgt);
    }
  }
}

// ---- logits + fused scatter: grid (257 tokens x 4 rowgroups) x 256 threads --
// R5-proven shape: 1028 blocks keeps the machine latency-tolerant; weights
// (520KB) are L2-resident so redundant reads are cheap. (R6's 16-row/257-block
// variant: 1 block/CU, serial chain 4x longer -> 205us. Reverted.)
__global__ void __launch_bounds__(256) k_logits(
    const float* __restrict__ embed, const float* __restrict__ root2,
    const float* __restrict__ hw1, const float* __restrict__ hb1,
    const float* __restrict__ hw2, const float* __restrict__ hb2,
    const int* __restrict__ bidx, const int* __restrict__ boff,
    float* __restrict__ out) {
  int tok = blockIdx.x, r0 = blockIdx.y * 4;
  int c = threadIdx.x;
  __shared__ float hrow[4][DIM];
  __shared__ float hid[4][DIM];
  __shared__ float tailred[4][17];
  __shared__ float tailv[4];
  {
    float ev = embed[(size_t)tok * DIM + c];
#pragma unroll
    for (int j = 0; j < 4; ++j) hrow[j][c] = ev + root2[(size_t)(r0 + j) * DIM + c];
  }
  __syncthreads();
  // GEMM1: col c over K=256, 4 rows
  {
    float a0 = hb1[c], a1 = a0, a2 = a0, a3 = a0;
    for (int kb = 0; kb < DIM; kb += 8) {
      float wv[8];
#pragma unroll
      for (int i = 0; i < 8; ++i) wv[i] = hw1[(size_t)(kb + i) * DIM + c];
#pragma unroll
      for (int i = 0; i < 8; ++i) {
        int k = kb + i;
        a0 = fmaf(hrow[0][k], wv[i], a0);
        a1 = fmaf(hrow[1][k], wv[i], a1);
        a2 = fmaf(hrow[2][k], wv[i], a2);
        a3 = fmaf(hrow[3][k], wv[i], a3);
      }
    }
    hid[0][c] = fmaxf(a0, 0.f); hid[1][c] = fmaxf(a1, 0.f);
    hid[2][c] = fmaxf(a2, 0.f); hid[3][c] = fmaxf(a3, 0.f);
  }
  __syncthreads();
  // GEMM2: cols 0..255 into registers
  float a0, a1, a2, a3;
  {
    a0 = hb2[c]; a1 = a0; a2 = a0; a3 = a0;
    for (int kb = 0; kb < DIM; kb += 8) {
      float wv[8];
#pragma unroll
      for (int i = 0; i < 8; ++i) wv[i] = hw2[(size_t)(kb + i) * VOCAB + c];
#pragma unroll
      for (int i = 0; i < 8; ++i) {
        int k = kb + i;
        a0 = fmaf(hid[0][k], wv[i], a0);
        a1 = fmaf(hid[1][k], wv[i], a1);
        a2 = fmaf(hid[2][k], wv[i], a2);
        a3 = fmaf(hid[3][k], wv[i], a3);
      }
    }
  }
  // tail column 256: 16-way K-split across first 64 threads
  if (c < 64) {
    int r = c >> 4, seg = c & 15;
    float sum = 0.f;
#pragma unroll 4
    for (int i = 0; i < 16; ++i) {
      int k = seg * 16 + i;
      sum = fmaf(hid[r][k], hw2[(size_t)k * VOCAB + 256], sum);
    }
    tailred[r][seg] = sum;
  }
  __syncthreads();
  if (c < 4) {
    float a = hb2[256];
#pragma unroll
    for (int s = 0; s < 16; ++s) a += tailred[c][s];
    tailv[c] = a;
  }
  __syncthreads();
  // fused scatter: write this row to every matching t (coalesced 1KB rows)
#pragma unroll
  for (int j = 0; j < 4; ++j) {
    int b = r0 + j;
    int s = boff[b * (VOCAB + 1) + tok];
    int e = boff[b * (VOCAB + 1) + tok + 1];
    float aj = (j == 0) ? a0 : (j == 1) ? a1 : (j == 2) ? a2 : a3;
    float tl = tailv[j];
    for (int m = s; m < e; ++m) {
      int t = bidx[b * TT + m];
      size_t base = (size_t)(b * TT + t) * VOCAB;
      out[base + c] = aj;
      if (c == 0) out[base + 256] = tl;
    }
  }
}

extern "C" void kernel_launch(void* const* d_in, const int* in_sizes, int n_in,
                              void* d_out, int out_size, void* d_ws, size_t ws_size,
                              hipStream_t stream) {
  (void)in_sizes; (void)n_in; (void)out_size; (void)ws_size;
  const int*   tokens     = (const int*)d_in[0];
  const float* embed      = (const float*)d_in[1];
  const float* pin_w      = (const float*)d_in[2];
  const float* pin_b      = (const float*)d_in[3];
  const float* pch_w      = (const float*)d_in[4];
  const float* pch_b      = (const float*)d_in[5];
  const float* depth_bias = (const float*)d_in[6];
  // d_in[7..10] = q_w,q_b,k_w,k_b: provably unused (uniform softmax)
  const float* v_w        = (const float*)d_in[11];
  const float* v_b        = (const float*)d_in[12];
  const float* o_w        = (const float*)d_in[13];
  const float* o_b        = (const float*)d_in[14];
  const float* level_gate = (const float*)d_in[15];
  const float* depth_gate = (const float*)d_in[16];
  const float* in_proj_w  = (const float*)d_in[17];
  const float* in_proj_b  = (const float*)d_in[18];
  const float* out_proj_w = (const float*)d_in[19];
  const float* out_proj_b = (const float*)d_in[20];
  const float* ln_g       = (const float*)d_in[21];
  const float* ln_b       = (const float*)d_in[22];
  const float* ic_gate    = (const float*)d_in[23];
  const float* gate_w     = (const float*)d_in[24];
  const float* gate_b     = (const float*)d_in[25];
  const float* ew1        = (const float*)d_in[26];
  const float* eb1        = (const float*)d_in[27];
  const float* ew2        = (const float*)d_in[28];
  const float* eb2        = (const float*)d_in[29];
  const float* hw1        = (const float*)d_in[30];
  const float* hb1        = (const float*)d_in[31];
  const float* hw2        = (const float*)d_in[32];
  const float* hb2        = (const float*)d_in[33];
  float* out = (float*)d_out;

  float* ws      = (float*)d_ws;
  float* rootA   = ws + 4096;            // 4096 floats
  float* root2   = ws + 8192;            // 4096 floats
  int*   bidx    = (int*)(ws + 43136);   // 16*2048 = 32768 ints
  int*   boff    = (int*)(ws + 75904);   // 16*258  =  4128 ints

  k_fractal<<<256, 1024, 0, stream>>>(tokens, embed, pin_w, pin_b, pch_w, pch_b,
                                      depth_bias, v_w, v_b, o_w, o_b, level_gate,
                                      depth_gate, in_proj_w, in_proj_b, out_proj_w,
                                      out_proj_b, ln_g, ln_b, ic_gate, rootA, root2,
                                      bidx, boff);
  k_moe<<<256, 256, 0, stream>>>(rootA, gate_w, gate_b, ew1, eb1,
                                 ew2, eb2, root2);
  k_logits<<<dim3(VOCAB, 4), 256, 0, stream>>>(embed, root2, hw1, hb1, hw2, hb2,
                                               bidx, boff, out);
}